// Round 1
// baseline (777.019 us; speedup 1.0000x reference)
//
#include <hip/hip_runtime.h>

#define INC  128
#define HIDC 128
#define OUTC 64

// ---------------- CSR build ----------------

__global__ __launch_bounds__(256) void hist_kernel(const int* __restrict__ dst,
                                                   int* __restrict__ cnt, int E) {
    int e = blockIdx.x * 256 + threadIdx.x;
    if (e < E) atomicAdd(&cnt[dst[e]], 1);
}

__global__ __launch_bounds__(256) void dinv_kernel(const int* __restrict__ cnt,
                                                   float* __restrict__ dinv, int n) {
    int i = blockIdx.x * 256 + threadIdx.x;
    if (i < n) dinv[i] = rsqrtf((float)(cnt[i] + 1));  // +1 self-loop
}

// single-block exclusive scan of cnt[0..n) -> rowptr[0..n]
__global__ __launch_bounds__(1024) void scan_kernel(const int* __restrict__ cnt,
                                                    int* __restrict__ rowptr, int n) {
    __shared__ int sums[1024];
    const int tid = threadIdx.x;
    const int chunk = (n + 1023) >> 10;
    const int start = tid * chunk;
    const int endi  = min(start + chunk, n);
    int s = 0;
    for (int i = start; i < endi; ++i) s += cnt[i];
    sums[tid] = s;
    __syncthreads();
    for (int d = 1; d < 1024; d <<= 1) {
        int t = sums[tid];
        int a = (tid >= d) ? sums[tid - d] : 0;
        __syncthreads();
        sums[tid] = t + a;
        __syncthreads();
    }
    int off = sums[tid] - s;  // exclusive prefix
    for (int i = start; i < endi; ++i) { rowptr[i] = off; off += cnt[i]; }
    if (tid == 1023) rowptr[n] = sums[1023];
}

__global__ __launch_bounds__(256) void fill_kernel(const int* __restrict__ src,
                                                   const int* __restrict__ dst,
                                                   const int* __restrict__ rowptr,
                                                   int* __restrict__ fillc,
                                                   int* __restrict__ col, int E) {
    int e = blockIdx.x * 256 + threadIdx.x;
    if (e < E) {
        int d = dst[e];
        int p = atomicAdd(&fillc[d], 1);
        col[rowptr[d] + p] = src[e];
    }
}

// ---------------- fp32 tiled GEMM, epilogue scales row by dinv ----------------
// out[r][c] = dinv[r] * sum_k A[r][k] * W[k][c]  ; A is [M,128], W is [128,BN]

template <int BM, int BN, int BK, int TM, int TN>
__global__ __launch_bounds__(256) void gemm_scale_kernel(const float* __restrict__ A,
                                                         const float* __restrict__ W,
                                                         const float* __restrict__ dinv,
                                                         float* __restrict__ out, int M) {
    static_assert(TM == 4, "A fragment read assumes float4");
    constexpr int K   = 128;
    constexpr int LDA = BM + 4;   // 68 floats = 272B, 16B-aligned rows
    constexpr int LDB = BN + 4;
    __shared__ __align__(16) float As[BK][LDA];   // transposed: As[k][r]
    __shared__ __align__(16) float Ws[BK][LDB];

    const int tid  = threadIdx.x;
    const int row0 = blockIdx.x * BM;
    constexpr int NTC = BN / TN;          // threads per row of C-tile
    const int tr = tid / NTC;
    const int tc = tid % NTC;

    float acc[TM][TN];
#pragma unroll
    for (int m = 0; m < TM; ++m)
#pragma unroll
        for (int n = 0; n < TN; ++n) acc[m][n] = 0.f;

    for (int k0 = 0; k0 < K; k0 += BK) {
        // A tile: BM x BK, store transposed
#pragma unroll
        for (int i = tid; i < BM * BK / 4; i += 256) {
            int r  = i / (BK / 4);
            int c4 = (i % (BK / 4)) * 4;
            float4 v = make_float4(0.f, 0.f, 0.f, 0.f);
            int grow = row0 + r;
            if (grow < M) v = *(const float4*)&A[(size_t)grow * K + k0 + c4];
            As[c4 + 0][r] = v.x; As[c4 + 1][r] = v.y;
            As[c4 + 2][r] = v.z; As[c4 + 3][r] = v.w;
        }
        // W tile: BK x BN
#pragma unroll
        for (int i = tid; i < BK * BN / 4; i += 256) {
            int kk = i / (BN / 4);
            int c4 = (i % (BN / 4)) * 4;
            *(float4*)&Ws[kk][c4] = *(const float4*)&W[(size_t)(k0 + kk) * BN + c4];
        }
        __syncthreads();
#pragma unroll
        for (int k = 0; k < BK; ++k) {
            float a[TM], b[TN];
            *(float4*)&a[0] = *(const float4*)&As[k][tr * TM];
#pragma unroll
            for (int n4 = 0; n4 < TN; n4 += 4)
                *(float4*)&b[n4] = *(const float4*)&Ws[k][tc * TN + n4];
#pragma unroll
            for (int m = 0; m < TM; ++m)
#pragma unroll
                for (int n = 0; n < TN; ++n)
                    acc[m][n] = fmaf(a[m], b[n], acc[m][n]);
        }
        __syncthreads();
    }
#pragma unroll
    for (int m = 0; m < TM; ++m) {
        int grow = row0 + tr * TM + m;
        if (grow < M) {
            float sc = dinv[grow];
#pragma unroll
            for (int n4 = 0; n4 < TN; n4 += 4) {
                float4 o;
                o.x = acc[m][n4 + 0] * sc; o.y = acc[m][n4 + 1] * sc;
                o.z = acc[m][n4 + 2] * sc; o.w = acc[m][n4 + 3] * sc;
                *(float4*)&out[(size_t)grow * BN + tc * TN + n4] = o;
            }
        }
    }
}

// ---------------- aggregation: one wave per node ----------------
// h1[v] = relu(dinv[v] * (g[v] + sum_{u->v} g[u]) + b1)   (128 ch: float2/lane)

__global__ __launch_bounds__(256) void agg1_kernel(const float* __restrict__ g,
                                                   const int* __restrict__ rowptr,
                                                   const int* __restrict__ col,
                                                   const float* __restrict__ dinv,
                                                   const float* __restrict__ b1,
                                                   float* __restrict__ h1, int n) {
    const int wid  = threadIdx.x >> 6;
    const int lane = threadIdx.x & 63;
    const int v = blockIdx.x * 4 + wid;
    if (v >= n) return;
    const int base = rowptr[v], endi = rowptr[v + 1];
    float2 acc = *(const float2*)&g[(size_t)v * HIDC + lane * 2];
    for (int e = base; e < endi; ++e) {
        int u = col[e];
        const float2 gu = *(const float2*)&g[(size_t)u * HIDC + lane * 2];
        acc.x += gu.x; acc.y += gu.y;
    }
    const float dv = dinv[v];
    const float2 bb = *(const float2*)&b1[lane * 2];
    float o0 = fmaxf(fmaf(dv, acc.x, bb.x), 0.f);
    float o1 = fmaxf(fmaf(dv, acc.y, bb.y), 0.f);
    *(float2*)&h1[(size_t)v * HIDC + lane * 2] = make_float2(o0, o1);
}

// h2[v] = dinv[v]*(g2[v] + sum g2[u]) + b2 ; out[v] = h2 @ Wfc + bfc   (64 ch: 1/lane)

__global__ __launch_bounds__(256) void agg2_fc_kernel(const float* __restrict__ g2,
                                                      const int* __restrict__ rowptr,
                                                      const int* __restrict__ col,
                                                      const float* __restrict__ dinv,
                                                      const float* __restrict__ b2,
                                                      const float* __restrict__ Wfc,
                                                      const float* __restrict__ bfc,
                                                      float* __restrict__ out, int n) {
    __shared__ float h2s[4][OUTC];
    const int wid  = threadIdx.x >> 6;
    const int lane = threadIdx.x & 63;
    const int v = blockIdx.x * 4 + wid;
    const bool valid = v < n;
    float h2 = 0.f;
    if (valid) {
        const int base = rowptr[v], endi = rowptr[v + 1];
        float acc = g2[(size_t)v * OUTC + lane];
        for (int e = base; e < endi; ++e) {
            int u = col[e];
            acc += g2[(size_t)u * OUTC + lane];
        }
        h2 = fmaf(dinv[v], acc, b2[lane]);
    }
    h2s[wid][lane] = h2;
    __syncthreads();
    if (valid) {
        float fc = bfc[lane];
#pragma unroll 8
        for (int c = 0; c < OUTC; ++c)
            fc = fmaf(h2s[wid][c], Wfc[c * OUTC + lane], fc);
        out[(size_t)v * OUTC + lane] = fc;
    }
}

// ---------------- launch ----------------

extern "C" void kernel_launch(void* const* d_in, const int* in_sizes, int n_in,
                              void* d_out, int out_size, void* d_ws, size_t ws_size,
                              hipStream_t stream) {
    const float* x   = (const float*)d_in[0];
    const int*   ei  = (const int*)d_in[1];
    const float* W1  = (const float*)d_in[2];
    const float* b1  = (const float*)d_in[3];
    const float* W2  = (const float*)d_in[4];
    const float* b2  = (const float*)d_in[5];
    const float* Wfc = (const float*)d_in[6];
    const float* bfc = (const float*)d_in[7];
    float* out = (float*)d_out;

    const int n = in_sizes[0] / INC;
    const int E = in_sizes[1] / 2;
    const int* src = ei;
    const int* dst = ei + E;

    char* w = (char*)d_ws;
    auto alloc = [&](size_t bytes) -> void* {
        void* p = (void*)w;
        w += (bytes + 255) & ~(size_t)255;
        return p;
    };
    int*   cnt    = (int*)alloc((size_t)n * 4);
    int*   fillc  = (int*)alloc((size_t)n * 4);
    int*   rowptr = (int*)alloc((size_t)(n + 1) * 4);
    float* dinvp  = (float*)alloc((size_t)n * 4);
    int*   col    = (int*)alloc((size_t)E * 4);
    float* g      = (float*)alloc((size_t)n * HIDC * 4);  // g1, reused as g2
    float* h1     = (float*)alloc((size_t)n * HIDC * 4);

    hipMemsetAsync(cnt, 0, (size_t)n * 4, stream);
    hipMemsetAsync(fillc, 0, (size_t)n * 4, stream);

    hist_kernel<<<(E + 255) / 256, 256, 0, stream>>>(dst, cnt, E);
    dinv_kernel<<<(n + 255) / 256, 256, 0, stream>>>(cnt, dinvp, n);
    scan_kernel<<<1, 1024, 0, stream>>>(cnt, rowptr, n);
    fill_kernel<<<(E + 255) / 256, 256, 0, stream>>>(src, dst, rowptr, fillc, col, E);

    // layer 1: g = (x @ W1) * dinv ; h1 = relu(dinv*(g[v]+sum g[u]) + b1)
    gemm_scale_kernel<64, 128, 32, 4, 8><<<(n + 63) / 64, 256, 0, stream>>>(x, W1, dinvp, g, n);
    agg1_kernel<<<(n + 3) / 4, 256, 0, stream>>>(g, rowptr, col, dinvp, b1, h1, n);

    // layer 2: g2 = (h1 @ W2) * dinv ; h2 = dinv*(g2[v]+sum g2[u]) + b2 ; out = h2@Wfc+bfc
    gemm_scale_kernel<64, 64, 32, 4, 4><<<(n + 63) / 64, 256, 0, stream>>>(h1, W2, dinvp, g, n);
    agg2_fc_kernel<<<(n + 3) / 4, 256, 0, stream>>>(g, rowptr, col, dinvp, b2, Wfc, bfc, out, n);
}

// Round 2
// 596.586 us; speedup vs baseline: 1.3024x; 1.3024x over previous
//
#include <hip/hip_runtime.h>

#define INC  128
#define HIDC 128
#define OUTC 64

// ---------------- CSR build ----------------

__global__ __launch_bounds__(256) void hist_kernel(const int* __restrict__ dst,
                                                   int* __restrict__ cnt, int E) {
    int e = blockIdx.x * 256 + threadIdx.x;
    if (e < E) atomicAdd(&cnt[dst[e]], 1);
}

__global__ __launch_bounds__(256) void dinv_kernel(const int* __restrict__ cnt,
                                                   float* __restrict__ dinv, int n) {
    int i = blockIdx.x * 256 + threadIdx.x;
    if (i < n) dinv[i] = rsqrtf((float)(cnt[i] + 1));  // +1 self-loop
}

// single-block exclusive scan of cnt[0..n) -> rowptr[0..n]
__global__ __launch_bounds__(1024) void scan_kernel(const int* __restrict__ cnt,
                                                    int* __restrict__ rowptr, int n) {
    __shared__ int sums[1024];
    const int tid = threadIdx.x;
    const int chunk = (n + 1023) >> 10;
    const int start = tid * chunk;
    const int endi  = min(start + chunk, n);
    int s = 0;
    for (int i = start; i < endi; ++i) s += cnt[i];
    sums[tid] = s;
    __syncthreads();
    for (int d = 1; d < 1024; d <<= 1) {
        int t = sums[tid];
        int a = (tid >= d) ? sums[tid - d] : 0;
        __syncthreads();
        sums[tid] = t + a;
        __syncthreads();
    }
    int off = sums[tid] - s;  // exclusive prefix
    for (int i = start; i < endi; ++i) { rowptr[i] = off; off += cnt[i]; }
    if (tid == 1023) rowptr[n] = sums[1023];
}

__global__ __launch_bounds__(256) void fill_kernel(const int* __restrict__ src,
                                                   const int* __restrict__ dst,
                                                   const int* __restrict__ rowptr,
                                                   int* __restrict__ fillc,
                                                   int* __restrict__ col, int E) {
    int e = blockIdx.x * 256 + threadIdx.x;
    if (e < E) {
        int d = dst[e];
        int p = atomicAdd(&fillc[d], 1);
        col[rowptr[d] + p] = src[e];
    }
}

// fold FC into layer-2 weights: W2f = W2 @ Wfc  [128x64], b2f = b2 @ Wfc + bfc [64]
__global__ __launch_bounds__(256) void fold_kernel(const float* __restrict__ W2,
                                                   const float* __restrict__ Wfc,
                                                   const float* __restrict__ b2,
                                                   const float* __restrict__ bfc,
                                                   float* __restrict__ W2f,
                                                   float* __restrict__ b2f) {
    int t = blockIdx.x * 256 + threadIdx.x;
    if (t < HIDC * OUTC) {
        int i = t >> 6, j = t & 63;
        float s = 0.f;
#pragma unroll 8
        for (int k = 0; k < OUTC; ++k) s = fmaf(W2[i * OUTC + k], Wfc[k * OUTC + j], s);
        W2f[t] = s;
    } else if (t < HIDC * OUTC + OUTC) {
        int j = t - HIDC * OUTC;
        float s = bfc[j];
#pragma unroll 8
        for (int k = 0; k < OUTC; ++k) s = fmaf(b2[k], Wfc[k * OUTC + j], s);
        b2f[j] = s;
    }
}

// ---------------- fp32 tiled GEMM, epilogue scales row by dinv ----------------

template <int BM, int BN, int BK, int TM, int TN>
__global__ __launch_bounds__(256) void gemm_scale_kernel(const float* __restrict__ A,
                                                         const float* __restrict__ W,
                                                         const float* __restrict__ dinv,
                                                         float* __restrict__ out, int M) {
    static_assert(TM == 4, "A fragment read assumes float4");
    constexpr int K   = 128;
    constexpr int LDA = BM + 4;
    constexpr int LDB = BN + 4;
    __shared__ __align__(16) float As[BK][LDA];   // transposed: As[k][r]
    __shared__ __align__(16) float Ws[BK][LDB];

    const int tid  = threadIdx.x;
    const int row0 = blockIdx.x * BM;
    constexpr int NTC = BN / TN;
    const int tr = tid / NTC;
    const int tc = tid % NTC;

    float acc[TM][TN];
#pragma unroll
    for (int m = 0; m < TM; ++m)
#pragma unroll
        for (int n = 0; n < TN; ++n) acc[m][n] = 0.f;

    for (int k0 = 0; k0 < K; k0 += BK) {
#pragma unroll
        for (int i = tid; i < BM * BK / 4; i += 256) {
            int r  = i / (BK / 4);
            int c4 = (i % (BK / 4)) * 4;
            float4 v = make_float4(0.f, 0.f, 0.f, 0.f);
            int grow = row0 + r;
            if (grow < M) v = *(const float4*)&A[(size_t)grow * K + k0 + c4];
            As[c4 + 0][r] = v.x; As[c4 + 1][r] = v.y;
            As[c4 + 2][r] = v.z; As[c4 + 3][r] = v.w;
        }
#pragma unroll
        for (int i = tid; i < BK * BN / 4; i += 256) {
            int kk = i / (BN / 4);
            int c4 = (i % (BN / 4)) * 4;
            *(float4*)&Ws[kk][c4] = *(const float4*)&W[(size_t)(k0 + kk) * BN + c4];
        }
        __syncthreads();
#pragma unroll
        for (int k = 0; k < BK; ++k) {
            float a[TM], b[TN];
            *(float4*)&a[0] = *(const float4*)&As[k][tr * TM];
#pragma unroll
            for (int n4 = 0; n4 < TN; n4 += 4)
                *(float4*)&b[n4] = *(const float4*)&Ws[k][tc * TN + n4];
#pragma unroll
            for (int m = 0; m < TM; ++m)
#pragma unroll
                for (int n = 0; n < TN; ++n)
                    acc[m][n] = fmaf(a[m], b[n], acc[m][n]);
        }
        __syncthreads();
    }
#pragma unroll
    for (int m = 0; m < TM; ++m) {
        int grow = row0 + tr * TM + m;
        if (grow < M) {
            float sc = dinv[grow];
#pragma unroll
            for (int n4 = 0; n4 < TN; n4 += 4) {
                float4 o;
                o.x = acc[m][n4 + 0] * sc; o.y = acc[m][n4 + 1] * sc;
                o.z = acc[m][n4 + 2] * sc; o.w = acc[m][n4 + 3] * sc;
                *(float4*)&out[(size_t)grow * BN + tc * TN + n4] = o;
            }
        }
    }
}

// ---------------- aggregation: one wave per node, shfl-broadcast indices,
// ---------------- 8-wide unrolled gathers for memory-level parallelism ----

__global__ __launch_bounds__(256) void agg1_kernel(const float* __restrict__ g,
                                                   const int* __restrict__ rowptr,
                                                   const int* __restrict__ col,
                                                   const float* __restrict__ dinv,
                                                   const float* __restrict__ b1,
                                                   float* __restrict__ h1, int n) {
    const int wid  = threadIdx.x >> 6;
    const int lane = threadIdx.x & 63;
    const int v = blockIdx.x * 4 + wid;
    if (v >= n) return;
    const int base = rowptr[v], endi = rowptr[v + 1];
    const size_t coff = (size_t)lane * 2;

    float2 a0 = *(const float2*)&g[(size_t)v * HIDC + coff];
    float a1x = 0.f, a1y = 0.f, a2x = 0.f, a2y = 0.f, a3x = 0.f, a3y = 0.f;
    float a4x = 0.f, a4y = 0.f, a5x = 0.f, a5y = 0.f, a6x = 0.f, a6y = 0.f, a7x = 0.f, a7y = 0.f;

    for (int c = base; c < endi; c += 64) {
        const int m = min(64, endi - c);
        const int idx = col[c + min(lane, m - 1)];
        for (int i = 0; i < m; i += 8) {
            int u0 = __shfl(idx, i);
            int u1 = __shfl(idx, min(i + 1, m - 1));
            int u2 = __shfl(idx, min(i + 2, m - 1));
            int u3 = __shfl(idx, min(i + 3, m - 1));
            int u4 = __shfl(idx, min(i + 4, m - 1));
            int u5 = __shfl(idx, min(i + 5, m - 1));
            int u6 = __shfl(idx, min(i + 6, m - 1));
            int u7 = __shfl(idx, min(i + 7, m - 1));
            float w1 = (i + 1 < m) ? 1.f : 0.f;
            float w2 = (i + 2 < m) ? 1.f : 0.f;
            float w3 = (i + 3 < m) ? 1.f : 0.f;
            float w4 = (i + 4 < m) ? 1.f : 0.f;
            float w5 = (i + 5 < m) ? 1.f : 0.f;
            float w6 = (i + 6 < m) ? 1.f : 0.f;
            float w7 = (i + 7 < m) ? 1.f : 0.f;
            float2 x0 = *(const float2*)&g[(size_t)u0 * HIDC + coff];
            float2 x1 = *(const float2*)&g[(size_t)u1 * HIDC + coff];
            float2 x2 = *(const float2*)&g[(size_t)u2 * HIDC + coff];
            float2 x3 = *(const float2*)&g[(size_t)u3 * HIDC + coff];
            float2 x4 = *(const float2*)&g[(size_t)u4 * HIDC + coff];
            float2 x5 = *(const float2*)&g[(size_t)u5 * HIDC + coff];
            float2 x6 = *(const float2*)&g[(size_t)u6 * HIDC + coff];
            float2 x7 = *(const float2*)&g[(size_t)u7 * HIDC + coff];
            a0.x += x0.x;              a0.y += x0.y;
            a1x = fmaf(w1, x1.x, a1x); a1y = fmaf(w1, x1.y, a1y);
            a2x = fmaf(w2, x2.x, a2x); a2y = fmaf(w2, x2.y, a2y);
            a3x = fmaf(w3, x3.x, a3x); a3y = fmaf(w3, x3.y, a3y);
            a4x = fmaf(w4, x4.x, a4x); a4y = fmaf(w4, x4.y, a4y);
            a5x = fmaf(w5, x5.x, a5x); a5y = fmaf(w5, x5.y, a5y);
            a6x = fmaf(w6, x6.x, a6x); a6y = fmaf(w6, x6.y, a6y);
            a7x = fmaf(w7, x7.x, a7x); a7y = fmaf(w7, x7.y, a7y);
        }
    }
    float sx = a0.x + a1x + a2x + a3x + a4x + a5x + a6x + a7x;
    float sy = a0.y + a1y + a2y + a3y + a4y + a5y + a6y + a7y;
    const float dv = dinv[v];
    const float2 bb = *(const float2*)&b1[coff];
    float o0 = fmaxf(fmaf(dv, sx, bb.x), 0.f);
    float o1 = fmaxf(fmaf(dv, sy, bb.y), 0.f);
    *(float2*)&h1[(size_t)v * HIDC + coff] = make_float2(o0, o1);
}

// out[v] = dinv[v]*(g2[v] + sum g2[u]) + b2f   (FC already folded into W2f/b2f)
__global__ __launch_bounds__(256) void agg2_kernel(const float* __restrict__ g2,
                                                   const int* __restrict__ rowptr,
                                                   const int* __restrict__ col,
                                                   const float* __restrict__ dinv,
                                                   const float* __restrict__ b2f,
                                                   float* __restrict__ out, int n) {
    const int wid  = threadIdx.x >> 6;
    const int lane = threadIdx.x & 63;
    const int v = blockIdx.x * 4 + wid;
    if (v >= n) return;
    const int base = rowptr[v], endi = rowptr[v + 1];

    float a0 = g2[(size_t)v * OUTC + lane];
    float a1 = 0.f, a2 = 0.f, a3 = 0.f, a4 = 0.f, a5 = 0.f, a6 = 0.f, a7 = 0.f;

    for (int c = base; c < endi; c += 64) {
        const int m = min(64, endi - c);
        const int idx = col[c + min(lane, m - 1)];
        for (int i = 0; i < m; i += 8) {
            int u0 = __shfl(idx, i);
            int u1 = __shfl(idx, min(i + 1, m - 1));
            int u2 = __shfl(idx, min(i + 2, m - 1));
            int u3 = __shfl(idx, min(i + 3, m - 1));
            int u4 = __shfl(idx, min(i + 4, m - 1));
            int u5 = __shfl(idx, min(i + 5, m - 1));
            int u6 = __shfl(idx, min(i + 6, m - 1));
            int u7 = __shfl(idx, min(i + 7, m - 1));
            float w1 = (i + 1 < m) ? 1.f : 0.f;
            float w2 = (i + 2 < m) ? 1.f : 0.f;
            float w3 = (i + 3 < m) ? 1.f : 0.f;
            float w4 = (i + 4 < m) ? 1.f : 0.f;
            float w5 = (i + 5 < m) ? 1.f : 0.f;
            float w6 = (i + 6 < m) ? 1.f : 0.f;
            float w7 = (i + 7 < m) ? 1.f : 0.f;
            float x0 = g2[(size_t)u0 * OUTC + lane];
            float x1 = g2[(size_t)u1 * OUTC + lane];
            float x2 = g2[(size_t)u2 * OUTC + lane];
            float x3 = g2[(size_t)u3 * OUTC + lane];
            float x4 = g2[(size_t)u4 * OUTC + lane];
            float x5 = g2[(size_t)u5 * OUTC + lane];
            float x6 = g2[(size_t)u6 * OUTC + lane];
            float x7 = g2[(size_t)u7 * OUTC + lane];
            a0 += x0;
            a1 = fmaf(w1, x1, a1);
            a2 = fmaf(w2, x2, a2);
            a3 = fmaf(w3, x3, a3);
            a4 = fmaf(w4, x4, a4);
            a5 = fmaf(w5, x5, a5);
            a6 = fmaf(w6, x6, a6);
            a7 = fmaf(w7, x7, a7);
        }
    }
    float s = ((a0 + a1) + (a2 + a3)) + ((a4 + a5) + (a6 + a7));
    out[(size_t)v * OUTC + lane] = fmaf(dinv[v], s, b2f[lane]);
}

// ---------------- launch ----------------

extern "C" void kernel_launch(void* const* d_in, const int* in_sizes, int n_in,
                              void* d_out, int out_size, void* d_ws, size_t ws_size,
                              hipStream_t stream) {
    const float* x   = (const float*)d_in[0];
    const int*   ei  = (const int*)d_in[1];
    const float* W1  = (const float*)d_in[2];
    const float* b1  = (const float*)d_in[3];
    const float* W2  = (const float*)d_in[4];
    const float* b2  = (const float*)d_in[5];
    const float* Wfc = (const float*)d_in[6];
    const float* bfc = (const float*)d_in[7];
    float* out = (float*)d_out;

    const int n = in_sizes[0] / INC;
    const int E = in_sizes[1] / 2;
    const int* src = ei;
    const int* dst = ei + E;

    char* w = (char*)d_ws;
    auto alloc = [&](size_t bytes) -> void* {
        void* p = (void*)w;
        w += (bytes + 255) & ~(size_t)255;
        return p;
    };
    int*   cnt    = (int*)alloc((size_t)n * 4);
    int*   fillc  = (int*)alloc((size_t)n * 4);
    int*   rowptr = (int*)alloc((size_t)(n + 1) * 4);
    float* dinvp  = (float*)alloc((size_t)n * 4);
    int*   col    = (int*)alloc((size_t)E * 4);
    float* g      = (float*)alloc((size_t)n * HIDC * 4);  // g1, reused as g2
    float* h1     = (float*)alloc((size_t)n * HIDC * 4);
    float* W2f    = (float*)alloc((size_t)HIDC * OUTC * 4);
    float* b2f    = (float*)alloc((size_t)OUTC * 4);

    hipMemsetAsync(cnt, 0, (size_t)n * 4, stream);
    hipMemsetAsync(fillc, 0, (size_t)n * 4, stream);

    fold_kernel<<<(HIDC * OUTC + OUTC + 255) / 256, 256, 0, stream>>>(W2, Wfc, b2, bfc, W2f, b2f);
    hist_kernel<<<(E + 255) / 256, 256, 0, stream>>>(dst, cnt, E);
    dinv_kernel<<<(n + 255) / 256, 256, 0, stream>>>(cnt, dinvp, n);
    scan_kernel<<<1, 1024, 0, stream>>>(cnt, rowptr, n);
    fill_kernel<<<(E + 255) / 256, 256, 0, stream>>>(src, dst, rowptr, fillc, col, E);

    // layer 1: g = (x @ W1) * dinv ; h1 = relu(dinv*(g[v]+sum g[u]) + b1)
    gemm_scale_kernel<64, 128, 32, 4, 8><<<(n + 63) / 64, 256, 0, stream>>>(x, W1, dinvp, g, n);
    agg1_kernel<<<(n + 3) / 4, 256, 0, stream>>>(g, rowptr, col, dinvp, b1, h1, n);

    // layer 2 (+FC folded): g2 = (h1 @ W2f) * dinv ; out = dinv*(g2[v]+sum g2[u]) + b2f
    gemm_scale_kernel<64, 64, 32, 4, 4><<<(n + 63) / 64, 256, 0, stream>>>(h1, W2f, dinvp, g, n);
    agg2_kernel<<<(n + 3) / 4, 256, 0, stream>>>(g, rowptr, col, dinvp, b2f, out, n);
}

// Round 3
// 451.596 us; speedup vs baseline: 1.7206x; 1.3211x over previous
//
#include <hip/hip_runtime.h>

#define INC  128
#define HIDC 128
#define OUTC 64

// ---------------- CSR build ----------------

__global__ __launch_bounds__(256) void hist_kernel(const int* __restrict__ dst,
                                                   int* __restrict__ cnt, int E) {
    int e = blockIdx.x * 256 + threadIdx.x;
    if (e < E) atomicAdd(&cnt[dst[e]], 1);
}

__global__ __launch_bounds__(256) void dinv_kernel(const int* __restrict__ cnt,
                                                   float* __restrict__ dinv, int n) {
    int i = blockIdx.x * 256 + threadIdx.x;
    if (i < n) dinv[i] = rsqrtf((float)(cnt[i] + 1));  // +1 self-loop
}

// ---- hierarchical exclusive scan of cnt[0..n) -> rowptr[0..n] ----
// pass 1: per-block (1024 elems) sums
__global__ __launch_bounds__(256) void scan_part_kernel(const int* __restrict__ cnt,
                                                        int* __restrict__ bsum, int n) {
    const int tid = threadIdx.x;
    const int i = blockIdx.x * 1024 + tid * 4;
    int s = 0;
    if (i + 3 < n) {
        int4 v = *(const int4*)&cnt[i];
        s = v.x + v.y + v.z + v.w;
    } else {
        for (int k = 0; k < 4; ++k) if (i + k < n) s += cnt[i + k];
    }
#pragma unroll
    for (int d = 1; d < 64; d <<= 1) s += __shfl_xor(s, d);
    __shared__ int ws[4];
    if ((tid & 63) == 0) ws[tid >> 6] = s;
    __syncthreads();
    if (tid == 0) bsum[blockIdx.x] = ws[0] + ws[1] + ws[2] + ws[3];
}

// pass 2: exclusive scan of nb (<=1024) block sums
__global__ __launch_bounds__(1024) void scan_bsum_kernel(const int* __restrict__ bsum,
                                                         int* __restrict__ boff, int nb) {
    __shared__ int sums[1024];
    const int tid = threadIdx.x;
    int v = (tid < nb) ? bsum[tid] : 0;
    sums[tid] = v;
    __syncthreads();
    for (int d = 1; d < 1024; d <<= 1) {
        int t = sums[tid];
        int a = (tid >= d) ? sums[tid - d] : 0;
        __syncthreads();
        sums[tid] = t + a;
        __syncthreads();
    }
    if (tid < nb) boff[tid] = sums[tid] - v;
}

// pass 3: per-block exclusive scan + block offset -> rowptr
__global__ __launch_bounds__(256) void scan_final_kernel(const int* __restrict__ cnt,
                                                         const int* __restrict__ boff,
                                                         int* __restrict__ rowptr,
                                                         int n, int E) {
    __shared__ int tsum[256];
    const int tid = threadIdx.x;
    const int i = blockIdx.x * 1024 + tid * 4;
    int v0 = 0, v1 = 0, v2 = 0, v3 = 0;
    if (i + 3 < n) {
        int4 v = *(const int4*)&cnt[i];
        v0 = v.x; v1 = v.y; v2 = v.z; v3 = v.w;
    } else {
        if (i + 0 < n) v0 = cnt[i + 0];
        if (i + 1 < n) v1 = cnt[i + 1];
        if (i + 2 < n) v2 = cnt[i + 2];
        if (i + 3 < n) v3 = cnt[i + 3];
    }
    const int my = v0 + v1 + v2 + v3;
    tsum[tid] = my;
    __syncthreads();
    for (int d = 1; d < 256; d <<= 1) {
        int t = tsum[tid];
        int a = (tid >= d) ? tsum[tid - d] : 0;
        __syncthreads();
        tsum[tid] = t + a;
        __syncthreads();
    }
    int off = boff[blockIdx.x] + tsum[tid] - my;  // exclusive prefix for elem i
    if (i + 0 < n) rowptr[i + 0] = off;
    off += v0;
    if (i + 1 < n) rowptr[i + 1] = off;
    off += v1;
    if (i + 2 < n) rowptr[i + 2] = off;
    off += v2;
    if (i + 3 < n) rowptr[i + 3] = off;
    if (blockIdx.x == 0 && tid == 0) rowptr[n] = E;
}

__global__ __launch_bounds__(256) void fill_kernel(const int* __restrict__ src,
                                                   const int* __restrict__ dst,
                                                   const int* __restrict__ rowptr,
                                                   int* __restrict__ fillc,
                                                   int* __restrict__ col, int E) {
    int e = blockIdx.x * 256 + threadIdx.x;
    if (e < E) {
        int d = dst[e];
        int p = atomicAdd(&fillc[d], 1);
        col[rowptr[d] + p] = src[e];
    }
}

// fold FC into layer-2 weights: W2f = W2 @ Wfc  [128x64], b2f = b2 @ Wfc + bfc [64]
__global__ __launch_bounds__(256) void fold_kernel(const float* __restrict__ W2,
                                                   const float* __restrict__ Wfc,
                                                   const float* __restrict__ b2,
                                                   const float* __restrict__ bfc,
                                                   float* __restrict__ W2f,
                                                   float* __restrict__ b2f) {
    int t = blockIdx.x * 256 + threadIdx.x;
    if (t < HIDC * OUTC) {
        int i = t >> 6, j = t & 63;
        float s = 0.f;
#pragma unroll 8
        for (int k = 0; k < OUTC; ++k) s = fmaf(W2[i * OUTC + k], Wfc[k * OUTC + j], s);
        W2f[t] = s;
    } else if (t < HIDC * OUTC + OUTC) {
        int j = t - HIDC * OUTC;
        float s = bfc[j];
#pragma unroll 8
        for (int k = 0; k < OUTC; ++k) s = fmaf(b2[k], Wfc[k * OUTC + j], s);
        b2f[j] = s;
    }
}

// ---------------- fp32 tiled GEMM, epilogue scales row by dinv ----------------

template <int BM, int BN, int BK, int TM, int TN>
__global__ __launch_bounds__(256) void gemm_scale_kernel(const float* __restrict__ A,
                                                         const float* __restrict__ W,
                                                         const float* __restrict__ dinv,
                                                         float* __restrict__ out, int M) {
    static_assert(TM == 4, "A fragment read assumes float4");
    constexpr int K   = 128;
    constexpr int LDA = BM + 4;
    constexpr int LDB = BN + 4;
    __shared__ __align__(16) float As[BK][LDA];   // transposed: As[k][r]
    __shared__ __align__(16) float Ws[BK][LDB];

    const int tid  = threadIdx.x;
    const int row0 = blockIdx.x * BM;
    constexpr int NTC = BN / TN;
    const int tr = tid / NTC;
    const int tc = tid % NTC;

    float acc[TM][TN];
#pragma unroll
    for (int m = 0; m < TM; ++m)
#pragma unroll
        for (int n = 0; n < TN; ++n) acc[m][n] = 0.f;

    for (int k0 = 0; k0 < K; k0 += BK) {
#pragma unroll
        for (int i = tid; i < BM * BK / 4; i += 256) {
            int r  = i / (BK / 4);
            int c4 = (i % (BK / 4)) * 4;
            float4 v = make_float4(0.f, 0.f, 0.f, 0.f);
            int grow = row0 + r;
            if (grow < M) v = *(const float4*)&A[(size_t)grow * K + k0 + c4];
            As[c4 + 0][r] = v.x; As[c4 + 1][r] = v.y;
            As[c4 + 2][r] = v.z; As[c4 + 3][r] = v.w;
        }
#pragma unroll
        for (int i = tid; i < BK * BN / 4; i += 256) {
            int kk = i / (BN / 4);
            int c4 = (i % (BN / 4)) * 4;
            *(float4*)&Ws[kk][c4] = *(const float4*)&W[(size_t)(k0 + kk) * BN + c4];
        }
        __syncthreads();
#pragma unroll
        for (int k = 0; k < BK; ++k) {
            float a[TM], b[TN];
            *(float4*)&a[0] = *(const float4*)&As[k][tr * TM];
#pragma unroll
            for (int n4 = 0; n4 < TN; n4 += 4)
                *(float4*)&b[n4] = *(const float4*)&Ws[k][tc * TN + n4];
#pragma unroll
            for (int m = 0; m < TM; ++m)
#pragma unroll
                for (int n = 0; n < TN; ++n)
                    acc[m][n] = fmaf(a[m], b[n], acc[m][n]);
        }
        __syncthreads();
    }
#pragma unroll
    for (int m = 0; m < TM; ++m) {
        int grow = row0 + tr * TM + m;
        if (grow < M) {
            float sc = dinv[grow];
#pragma unroll
            for (int n4 = 0; n4 < TN; n4 += 4) {
                float4 o;
                o.x = acc[m][n4 + 0] * sc; o.y = acc[m][n4 + 1] * sc;
                o.z = acc[m][n4 + 2] * sc; o.w = acc[m][n4 + 3] * sc;
                *(float4*)&out[(size_t)grow * BN + tc * TN + n4] = o;
            }
        }
    }
}

// ---------------- aggregation: one wave per node, shfl-broadcast indices,
// ---------------- 8-wide unrolled gathers for memory-level parallelism ----

__global__ __launch_bounds__(256) void agg1_kernel(const float* __restrict__ g,
                                                   const int* __restrict__ rowptr,
                                                   const int* __restrict__ col,
                                                   const float* __restrict__ dinv,
                                                   const float* __restrict__ b1,
                                                   float* __restrict__ h1, int n) {
    const int wid  = threadIdx.x >> 6;
    const int lane = threadIdx.x & 63;
    const int v = blockIdx.x * 4 + wid;
    if (v >= n) return;
    const int base = rowptr[v], endi = rowptr[v + 1];
    const size_t coff = (size_t)lane * 2;

    float2 a0 = *(const float2*)&g[(size_t)v * HIDC + coff];
    float a1x = 0.f, a1y = 0.f, a2x = 0.f, a2y = 0.f, a3x = 0.f, a3y = 0.f;
    float a4x = 0.f, a4y = 0.f, a5x = 0.f, a5y = 0.f, a6x = 0.f, a6y = 0.f, a7x = 0.f, a7y = 0.f;

    for (int c = base; c < endi; c += 64) {
        const int m = min(64, endi - c);
        const int idx = col[c + min(lane, m - 1)];
        for (int i = 0; i < m; i += 8) {
            int u0 = __shfl(idx, i);
            int u1 = __shfl(idx, min(i + 1, m - 1));
            int u2 = __shfl(idx, min(i + 2, m - 1));
            int u3 = __shfl(idx, min(i + 3, m - 1));
            int u4 = __shfl(idx, min(i + 4, m - 1));
            int u5 = __shfl(idx, min(i + 5, m - 1));
            int u6 = __shfl(idx, min(i + 6, m - 1));
            int u7 = __shfl(idx, min(i + 7, m - 1));
            float w1 = (i + 1 < m) ? 1.f : 0.f;
            float w2 = (i + 2 < m) ? 1.f : 0.f;
            float w3 = (i + 3 < m) ? 1.f : 0.f;
            float w4 = (i + 4 < m) ? 1.f : 0.f;
            float w5 = (i + 5 < m) ? 1.f : 0.f;
            float w6 = (i + 6 < m) ? 1.f : 0.f;
            float w7 = (i + 7 < m) ? 1.f : 0.f;
            float2 x0 = *(const float2*)&g[(size_t)u0 * HIDC + coff];
            float2 x1 = *(const float2*)&g[(size_t)u1 * HIDC + coff];
            float2 x2 = *(const float2*)&g[(size_t)u2 * HIDC + coff];
            float2 x3 = *(const float2*)&g[(size_t)u3 * HIDC + coff];
            float2 x4 = *(const float2*)&g[(size_t)u4 * HIDC + coff];
            float2 x5 = *(const float2*)&g[(size_t)u5 * HIDC + coff];
            float2 x6 = *(const float2*)&g[(size_t)u6 * HIDC + coff];
            float2 x7 = *(const float2*)&g[(size_t)u7 * HIDC + coff];
            a0.x += x0.x;              a0.y += x0.y;
            a1x = fmaf(w1, x1.x, a1x); a1y = fmaf(w1, x1.y, a1y);
            a2x = fmaf(w2, x2.x, a2x); a2y = fmaf(w2, x2.y, a2y);
            a3x = fmaf(w3, x3.x, a3x); a3y = fmaf(w3, x3.y, a3y);
            a4x = fmaf(w4, x4.x, a4x); a4y = fmaf(w4, x4.y, a4y);
            a5x = fmaf(w5, x5.x, a5x); a5y = fmaf(w5, x5.y, a5y);
            a6x = fmaf(w6, x6.x, a6x); a6y = fmaf(w6, x6.y, a6y);
            a7x = fmaf(w7, x7.x, a7x); a7y = fmaf(w7, x7.y, a7y);
        }
    }
    float sx = a0.x + a1x + a2x + a3x + a4x + a5x + a6x + a7x;
    float sy = a0.y + a1y + a2y + a3y + a4y + a5y + a6y + a7y;
    const float dv = dinv[v];
    const float2 bb = *(const float2*)&b1[coff];
    float o0 = fmaxf(fmaf(dv, sx, bb.x), 0.f);
    float o1 = fmaxf(fmaf(dv, sy, bb.y), 0.f);
    *(float2*)&h1[(size_t)v * HIDC + coff] = make_float2(o0, o1);
}

// out[v] = dinv[v]*(g2[v] + sum g2[u]) + b2f   (FC already folded into W2f/b2f)
__global__ __launch_bounds__(256) void agg2_kernel(const float* __restrict__ g2,
                                                   const int* __restrict__ rowptr,
                                                   const int* __restrict__ col,
                                                   const float* __restrict__ dinv,
                                                   const float* __restrict__ b2f,
                                                   float* __restrict__ out, int n) {
    const int wid  = threadIdx.x >> 6;
    const int lane = threadIdx.x & 63;
    const int v = blockIdx.x * 4 + wid;
    if (v >= n) return;
    const int base = rowptr[v], endi = rowptr[v + 1];

    float a0 = g2[(size_t)v * OUTC + lane];
    float a1 = 0.f, a2 = 0.f, a3 = 0.f, a4 = 0.f, a5 = 0.f, a6 = 0.f, a7 = 0.f;

    for (int c = base; c < endi; c += 64) {
        const int m = min(64, endi - c);
        const int idx = col[c + min(lane, m - 1)];
        for (int i = 0; i < m; i += 8) {
            int u0 = __shfl(idx, i);
            int u1 = __shfl(idx, min(i + 1, m - 1));
            int u2 = __shfl(idx, min(i + 2, m - 1));
            int u3 = __shfl(idx, min(i + 3, m - 1));
            int u4 = __shfl(idx, min(i + 4, m - 1));
            int u5 = __shfl(idx, min(i + 5, m - 1));
            int u6 = __shfl(idx, min(i + 6, m - 1));
            int u7 = __shfl(idx, min(i + 7, m - 1));
            float w1 = (i + 1 < m) ? 1.f : 0.f;
            float w2 = (i + 2 < m) ? 1.f : 0.f;
            float w3 = (i + 3 < m) ? 1.f : 0.f;
            float w4 = (i + 4 < m) ? 1.f : 0.f;
            float w5 = (i + 5 < m) ? 1.f : 0.f;
            float w6 = (i + 6 < m) ? 1.f : 0.f;
            float w7 = (i + 7 < m) ? 1.f : 0.f;
            float x0 = g2[(size_t)u0 * OUTC + lane];
            float x1 = g2[(size_t)u1 * OUTC + lane];
            float x2 = g2[(size_t)u2 * OUTC + lane];
            float x3 = g2[(size_t)u3 * OUTC + lane];
            float x4 = g2[(size_t)u4 * OUTC + lane];
            float x5 = g2[(size_t)u5 * OUTC + lane];
            float x6 = g2[(size_t)u6 * OUTC + lane];
            float x7 = g2[(size_t)u7 * OUTC + lane];
            a0 += x0;
            a1 = fmaf(w1, x1, a1);
            a2 = fmaf(w2, x2, a2);
            a3 = fmaf(w3, x3, a3);
            a4 = fmaf(w4, x4, a4);
            a5 = fmaf(w5, x5, a5);
            a6 = fmaf(w6, x6, a6);
            a7 = fmaf(w7, x7, a7);
        }
    }
    float s = ((a0 + a1) + (a2 + a3)) + ((a4 + a5) + (a6 + a7));
    out[(size_t)v * OUTC + lane] = fmaf(dinv[v], s, b2f[lane]);
}

// ---------------- launch ----------------

extern "C" void kernel_launch(void* const* d_in, const int* in_sizes, int n_in,
                              void* d_out, int out_size, void* d_ws, size_t ws_size,
                              hipStream_t stream) {
    const float* x   = (const float*)d_in[0];
    const int*   ei  = (const int*)d_in[1];
    const float* W1  = (const float*)d_in[2];
    const float* b1  = (const float*)d_in[3];
    const float* W2  = (const float*)d_in[4];
    const float* b2  = (const float*)d_in[5];
    const float* Wfc = (const float*)d_in[6];
    const float* bfc = (const float*)d_in[7];
    float* out = (float*)d_out;

    const int n = in_sizes[0] / INC;
    const int E = in_sizes[1] / 2;
    const int* src = ei;
    const int* dst = ei + E;
    const int nb = (n + 1023) / 1024;

    char* w = (char*)d_ws;
    auto alloc = [&](size_t bytes) -> void* {
        void* p = (void*)w;
        w += (bytes + 255) & ~(size_t)255;
        return p;
    };
    int*   cnt    = (int*)alloc((size_t)n * 4);
    int*   fillc  = (int*)alloc((size_t)n * 4);
    int*   rowptr = (int*)alloc((size_t)(n + 1) * 4);
    float* dinvp  = (float*)alloc((size_t)n * 4);
    int*   col    = (int*)alloc((size_t)E * 4);
    float* g      = (float*)alloc((size_t)n * HIDC * 4);  // g1, reused as g2
    float* h1     = (float*)alloc((size_t)n * HIDC * 4);
    float* W2f    = (float*)alloc((size_t)HIDC * OUTC * 4);
    float* b2f    = (float*)alloc((size_t)OUTC * 4);
    int*   bsum   = (int*)alloc((size_t)nb * 4);
    int*   boff   = (int*)alloc((size_t)nb * 4);

    hipMemsetAsync(cnt, 0, (size_t)n * 4, stream);
    hipMemsetAsync(fillc, 0, (size_t)n * 4, stream);

    fold_kernel<<<(HIDC * OUTC + OUTC + 255) / 256, 256, 0, stream>>>(W2, Wfc, b2, bfc, W2f, b2f);
    hist_kernel<<<(E + 255) / 256, 256, 0, stream>>>(dst, cnt, E);
    dinv_kernel<<<(n + 255) / 256, 256, 0, stream>>>(cnt, dinvp, n);
    scan_part_kernel<<<nb, 256, 0, stream>>>(cnt, bsum, n);
    scan_bsum_kernel<<<1, 1024, 0, stream>>>(bsum, boff, nb);
    scan_final_kernel<<<nb, 256, 0, stream>>>(cnt, boff, rowptr, n, E);
    fill_kernel<<<(E + 255) / 256, 256, 0, stream>>>(src, dst, rowptr, fillc, col, E);

    // layer 1: g = (x @ W1) * dinv ; h1 = relu(dinv*(g[v]+sum g[u]) + b1)
    gemm_scale_kernel<64, 128, 32, 4, 8><<<(n + 63) / 64, 256, 0, stream>>>(x, W1, dinvp, g, n);
    agg1_kernel<<<(n + 3) / 4, 256, 0, stream>>>(g, rowptr, col, dinvp, b1, h1, n);

    // layer 2 (+FC folded): g2 = (h1 @ W2f) * dinv ; out = dinv*(g2[v]+sum g2[u]) + b2f
    gemm_scale_kernel<64, 64, 32, 4, 4><<<(n + 63) / 64, 256, 0, stream>>>(h1, W2f, dinvp, g, n);
    agg2_kernel<<<(n + 3) / 4, 256, 0, stream>>>(g, rowptr, col, dinvp, b2f, out, n);
}

// Round 4
// 398.868 us; speedup vs baseline: 1.9481x; 1.1322x over previous
//
#include <hip/hip_runtime.h>

#define INC  128
#define HIDC 128
#define OUTC 64

typedef unsigned int  u32;
typedef unsigned short u16;

// round-to-nearest-even f32 -> bf16 (as u16)
static __device__ __forceinline__ u16 f2bf(float f) {
    u32 u = __builtin_bit_cast(u32, f);
    u += 0x7fffu + ((u >> 16) & 1u);
    return (u16)(u >> 16);
}
static __device__ __forceinline__ float bf_lo(u32 u) {  // low ushort as bf16
    return __builtin_bit_cast(float, u << 16);
}
static __device__ __forceinline__ float bf_hi(u32 u) {  // high ushort as bf16
    return __builtin_bit_cast(float, u & 0xffff0000u);
}

// ---------------- CSR build ----------------

__global__ __launch_bounds__(256) void hist_kernel(const int* __restrict__ dst,
                                                   int* __restrict__ cnt, int E) {
    int e = blockIdx.x * 256 + threadIdx.x;
    if (e < E) atomicAdd(&cnt[dst[e]], 1);
}

__global__ __launch_bounds__(256) void dinv_kernel(const int* __restrict__ cnt,
                                                   float* __restrict__ dinv, int n) {
    int i = blockIdx.x * 256 + threadIdx.x;
    if (i < n) dinv[i] = rsqrtf((float)(cnt[i] + 1));  // +1 self-loop
}

// ---- hierarchical exclusive scan of cnt[0..n) -> rowptr[0..n] ----
__global__ __launch_bounds__(256) void scan_part_kernel(const int* __restrict__ cnt,
                                                        int* __restrict__ bsum, int n) {
    const int tid = threadIdx.x;
    const int i = blockIdx.x * 1024 + tid * 4;
    int s = 0;
    if (i + 3 < n) {
        int4 v = *(const int4*)&cnt[i];
        s = v.x + v.y + v.z + v.w;
    } else {
        for (int k = 0; k < 4; ++k) if (i + k < n) s += cnt[i + k];
    }
#pragma unroll
    for (int d = 1; d < 64; d <<= 1) s += __shfl_xor(s, d);
    __shared__ int ws[4];
    if ((tid & 63) == 0) ws[tid >> 6] = s;
    __syncthreads();
    if (tid == 0) bsum[blockIdx.x] = ws[0] + ws[1] + ws[2] + ws[3];
}

__global__ __launch_bounds__(1024) void scan_bsum_kernel(const int* __restrict__ bsum,
                                                         int* __restrict__ boff, int nb) {
    __shared__ int sums[1024];
    const int tid = threadIdx.x;
    int v = (tid < nb) ? bsum[tid] : 0;
    sums[tid] = v;
    __syncthreads();
    for (int d = 1; d < 1024; d <<= 1) {
        int t = sums[tid];
        int a = (tid >= d) ? sums[tid - d] : 0;
        __syncthreads();
        sums[tid] = t + a;
        __syncthreads();
    }
    if (tid < nb) boff[tid] = sums[tid] - v;
}

__global__ __launch_bounds__(256) void scan_final_kernel(const int* __restrict__ cnt,
                                                         const int* __restrict__ boff,
                                                         int* __restrict__ rowptr,
                                                         int n, int E) {
    __shared__ int tsum[256];
    const int tid = threadIdx.x;
    const int i = blockIdx.x * 1024 + tid * 4;
    int v0 = 0, v1 = 0, v2 = 0, v3 = 0;
    if (i + 3 < n) {
        int4 v = *(const int4*)&cnt[i];
        v0 = v.x; v1 = v.y; v2 = v.z; v3 = v.w;
    } else {
        if (i + 0 < n) v0 = cnt[i + 0];
        if (i + 1 < n) v1 = cnt[i + 1];
        if (i + 2 < n) v2 = cnt[i + 2];
        if (i + 3 < n) v3 = cnt[i + 3];
    }
    const int my = v0 + v1 + v2 + v3;
    tsum[tid] = my;
    __syncthreads();
    for (int d = 1; d < 256; d <<= 1) {
        int t = tsum[tid];
        int a = (tid >= d) ? tsum[tid - d] : 0;
        __syncthreads();
        tsum[tid] = t + a;
        __syncthreads();
    }
    int off = boff[blockIdx.x] + tsum[tid] - my;
    if (i + 0 < n) rowptr[i + 0] = off;
    off += v0;
    if (i + 1 < n) rowptr[i + 1] = off;
    off += v1;
    if (i + 2 < n) rowptr[i + 2] = off;
    off += v2;
    if (i + 3 < n) rowptr[i + 3] = off;
    if (blockIdx.x == 0 && tid == 0) rowptr[n] = E;
}

__global__ __launch_bounds__(256) void fill_kernel(const int* __restrict__ src,
                                                   const int* __restrict__ dst,
                                                   const int* __restrict__ rowptr,
                                                   int* __restrict__ fillc,
                                                   int* __restrict__ col, int E) {
    int e = blockIdx.x * 256 + threadIdx.x;
    if (e < E) {
        int d = dst[e];
        int p = atomicAdd(&fillc[d], 1);
        col[rowptr[d] + p] = src[e];
    }
}

// fold FC into layer-2 weights: W2f = W2 @ Wfc  [128x64], b2f = b2 @ Wfc + bfc [64]
__global__ __launch_bounds__(256) void fold_kernel(const float* __restrict__ W2,
                                                   const float* __restrict__ Wfc,
                                                   const float* __restrict__ b2,
                                                   const float* __restrict__ bfc,
                                                   float* __restrict__ W2f,
                                                   float* __restrict__ b2f) {
    int t = blockIdx.x * 256 + threadIdx.x;
    if (t < HIDC * OUTC) {
        int i = t >> 6, j = t & 63;
        float s = 0.f;
#pragma unroll 8
        for (int k = 0; k < OUTC; ++k) s = fmaf(W2[i * OUTC + k], Wfc[k * OUTC + j], s);
        W2f[t] = s;
    } else if (t < HIDC * OUTC + OUTC) {
        int j = t - HIDC * OUTC;
        float s = bfc[j];
#pragma unroll 8
        for (int k = 0; k < OUTC; ++k) s = fmaf(b2[k], Wfc[k * OUTC + j], s);
        b2f[j] = s;
    }
}

// ---------------- fp32 tiled GEMM -> bf16 output, epilogue scales row by dinv ----

template <int BM, int BN, int BK, int TM, int TN>
__global__ __launch_bounds__(256) void gemm_scale_bf16_kernel(const float* __restrict__ A,
                                                              const float* __restrict__ W,
                                                              const float* __restrict__ dinv,
                                                              u16* __restrict__ out, int M) {
    static_assert(TM == 4, "A fragment read assumes float4");
    constexpr int K   = 128;
    constexpr int LDA = BM + 4;
    constexpr int LDB = BN + 4;
    __shared__ __align__(16) float As[BK][LDA];   // transposed: As[k][r]
    __shared__ __align__(16) float Ws[BK][LDB];

    const int tid  = threadIdx.x;
    const int row0 = blockIdx.x * BM;
    constexpr int NTC = BN / TN;
    const int tr = tid / NTC;
    const int tc = tid % NTC;

    float acc[TM][TN];
#pragma unroll
    for (int m = 0; m < TM; ++m)
#pragma unroll
        for (int n = 0; n < TN; ++n) acc[m][n] = 0.f;

    for (int k0 = 0; k0 < K; k0 += BK) {
#pragma unroll
        for (int i = tid; i < BM * BK / 4; i += 256) {
            int r  = i / (BK / 4);
            int c4 = (i % (BK / 4)) * 4;
            float4 v = make_float4(0.f, 0.f, 0.f, 0.f);
            int grow = row0 + r;
            if (grow < M) v = *(const float4*)&A[(size_t)grow * K + k0 + c4];
            As[c4 + 0][r] = v.x; As[c4 + 1][r] = v.y;
            As[c4 + 2][r] = v.z; As[c4 + 3][r] = v.w;
        }
#pragma unroll
        for (int i = tid; i < BK * BN / 4; i += 256) {
            int kk = i / (BN / 4);
            int c4 = (i % (BN / 4)) * 4;
            *(float4*)&Ws[kk][c4] = *(const float4*)&W[(size_t)(k0 + kk) * BN + c4];
        }
        __syncthreads();
#pragma unroll
        for (int k = 0; k < BK; ++k) {
            float a[TM], b[TN];
            *(float4*)&a[0] = *(const float4*)&As[k][tr * TM];
#pragma unroll
            for (int n4 = 0; n4 < TN; n4 += 4)
                *(float4*)&b[n4] = *(const float4*)&Ws[k][tc * TN + n4];
#pragma unroll
            for (int m = 0; m < TM; ++m)
#pragma unroll
                for (int n = 0; n < TN; ++n)
                    acc[m][n] = fmaf(a[m], b[n], acc[m][n]);
        }
        __syncthreads();
    }
#pragma unroll
    for (int m = 0; m < TM; ++m) {
        int grow = row0 + tr * TM + m;
        if (grow < M) {
            float sc = dinv[grow];
            u32 p[TN / 2];
#pragma unroll
            for (int j = 0; j < TN / 2; ++j)
                p[j] = (u32)f2bf(acc[m][2 * j] * sc) | ((u32)f2bf(acc[m][2 * j + 1] * sc) << 16);
            u32* dstp = (u32*)(out + (size_t)grow * BN + tc * TN);
            if constexpr (TN == 8)      *(uint4*)dstp = *(uint4*)p;
            else if constexpr (TN == 4) *(uint2*)dstp = *(uint2*)p;
            else                        *dstp = p[0];
        }
    }
}

// ---------------- aggregation: one wave per node, shfl-broadcast indices,
// ---------------- 8-wide unrolled bf16 gathers ----------------------------

// h1[v] = relu(dinv[v] * (g[v] + sum g[u]) + b1)  ; g is bf16 [n][128], 2 ch/lane
__global__ __launch_bounds__(256) void agg1_kernel(const u32* __restrict__ g,   // bf16x2 words
                                                   const int* __restrict__ rowptr,
                                                   const int* __restrict__ col,
                                                   const float* __restrict__ dinv,
                                                   const float* __restrict__ b1,
                                                   float* __restrict__ h1, int n) {
    const int wid  = threadIdx.x >> 6;
    const int lane = threadIdx.x & 63;
    const int v = blockIdx.x * 4 + wid;
    if (v >= n) return;
    const int base = rowptr[v], endi = rowptr[v + 1];

    u32 uv = g[(size_t)v * 64 + lane];
    float a0x = bf_lo(uv), a0y = bf_hi(uv);
    float a1x = 0.f, a1y = 0.f, a2x = 0.f, a2y = 0.f, a3x = 0.f, a3y = 0.f;
    float a4x = 0.f, a4y = 0.f, a5x = 0.f, a5y = 0.f, a6x = 0.f, a6y = 0.f, a7x = 0.f, a7y = 0.f;

    for (int c = base; c < endi; c += 64) {
        const int m = min(64, endi - c);
        const int idx = col[c + min(lane, m - 1)];
        for (int i = 0; i < m; i += 8) {
            int u0 = __shfl(idx, i);
            int u1 = __shfl(idx, min(i + 1, m - 1));
            int u2 = __shfl(idx, min(i + 2, m - 1));
            int u3 = __shfl(idx, min(i + 3, m - 1));
            int u4 = __shfl(idx, min(i + 4, m - 1));
            int u5 = __shfl(idx, min(i + 5, m - 1));
            int u6 = __shfl(idx, min(i + 6, m - 1));
            int u7 = __shfl(idx, min(i + 7, m - 1));
            float w1 = (i + 1 < m) ? 1.f : 0.f;
            float w2 = (i + 2 < m) ? 1.f : 0.f;
            float w3 = (i + 3 < m) ? 1.f : 0.f;
            float w4 = (i + 4 < m) ? 1.f : 0.f;
            float w5 = (i + 5 < m) ? 1.f : 0.f;
            float w6 = (i + 6 < m) ? 1.f : 0.f;
            float w7 = (i + 7 < m) ? 1.f : 0.f;
            u32 x0 = g[(size_t)u0 * 64 + lane];
            u32 x1 = g[(size_t)u1 * 64 + lane];
            u32 x2 = g[(size_t)u2 * 64 + lane];
            u32 x3 = g[(size_t)u3 * 64 + lane];
            u32 x4 = g[(size_t)u4 * 64 + lane];
            u32 x5 = g[(size_t)u5 * 64 + lane];
            u32 x6 = g[(size_t)u6 * 64 + lane];
            u32 x7 = g[(size_t)u7 * 64 + lane];
            a0x += bf_lo(x0);                a0y += bf_hi(x0);
            a1x = fmaf(w1, bf_lo(x1), a1x);  a1y = fmaf(w1, bf_hi(x1), a1y);
            a2x = fmaf(w2, bf_lo(x2), a2x);  a2y = fmaf(w2, bf_hi(x2), a2y);
            a3x = fmaf(w3, bf_lo(x3), a3x);  a3y = fmaf(w3, bf_hi(x3), a3y);
            a4x = fmaf(w4, bf_lo(x4), a4x);  a4y = fmaf(w4, bf_hi(x4), a4y);
            a5x = fmaf(w5, bf_lo(x5), a5x);  a5y = fmaf(w5, bf_hi(x5), a5y);
            a6x = fmaf(w6, bf_lo(x6), a6x);  a6y = fmaf(w6, bf_hi(x6), a6y);
            a7x = fmaf(w7, bf_lo(x7), a7x);  a7y = fmaf(w7, bf_hi(x7), a7y);
        }
    }
    float sx = ((a0x + a1x) + (a2x + a3x)) + ((a4x + a5x) + (a6x + a7x));
    float sy = ((a0y + a1y) + (a2y + a3y)) + ((a4y + a5y) + (a6y + a7y));
    const float dv = dinv[v];
    const float2 bb = *(const float2*)&b1[lane * 2];
    float o0 = fmaxf(fmaf(dv, sx, bb.x), 0.f);
    float o1 = fmaxf(fmaf(dv, sy, bb.y), 0.f);
    *(float2*)&h1[(size_t)v * HIDC + (size_t)lane * 2] = make_float2(o0, o1);
}

// out[v] = dinv[v]*(g2[v] + sum g2[u]) + b2f ; g2 is bf16 [n][64], 1 ch/lane
__global__ __launch_bounds__(256) void agg2_kernel(const u16* __restrict__ g2,
                                                   const int* __restrict__ rowptr,
                                                   const int* __restrict__ col,
                                                   const float* __restrict__ dinv,
                                                   const float* __restrict__ b2f,
                                                   float* __restrict__ out, int n) {
    const int wid  = threadIdx.x >> 6;
    const int lane = threadIdx.x & 63;
    const int v = blockIdx.x * 4 + wid;
    if (v >= n) return;
    const int base = rowptr[v], endi = rowptr[v + 1];

    float a0 = __builtin_bit_cast(float, (u32)g2[(size_t)v * 64 + lane] << 16);
    float a1 = 0.f, a2 = 0.f, a3 = 0.f, a4 = 0.f, a5 = 0.f, a6 = 0.f, a7 = 0.f;

    for (int c = base; c < endi; c += 64) {
        const int m = min(64, endi - c);
        const int idx = col[c + min(lane, m - 1)];
        for (int i = 0; i < m; i += 8) {
            int u0 = __shfl(idx, i);
            int u1 = __shfl(idx, min(i + 1, m - 1));
            int u2 = __shfl(idx, min(i + 2, m - 1));
            int u3 = __shfl(idx, min(i + 3, m - 1));
            int u4 = __shfl(idx, min(i + 4, m - 1));
            int u5 = __shfl(idx, min(i + 5, m - 1));
            int u6 = __shfl(idx, min(i + 6, m - 1));
            int u7 = __shfl(idx, min(i + 7, m - 1));
            float w1 = (i + 1 < m) ? 1.f : 0.f;
            float w2 = (i + 2 < m) ? 1.f : 0.f;
            float w3 = (i + 3 < m) ? 1.f : 0.f;
            float w4 = (i + 4 < m) ? 1.f : 0.f;
            float w5 = (i + 5 < m) ? 1.f : 0.f;
            float w6 = (i + 6 < m) ? 1.f : 0.f;
            float w7 = (i + 7 < m) ? 1.f : 0.f;
            float x0 = __builtin_bit_cast(float, (u32)g2[(size_t)u0 * 64 + lane] << 16);
            float x1 = __builtin_bit_cast(float, (u32)g2[(size_t)u1 * 64 + lane] << 16);
            float x2 = __builtin_bit_cast(float, (u32)g2[(size_t)u2 * 64 + lane] << 16);
            float x3 = __builtin_bit_cast(float, (u32)g2[(size_t)u3 * 64 + lane] << 16);
            float x4 = __builtin_bit_cast(float, (u32)g2[(size_t)u4 * 64 + lane] << 16);
            float x5 = __builtin_bit_cast(float, (u32)g2[(size_t)u5 * 64 + lane] << 16);
            float x6 = __builtin_bit_cast(float, (u32)g2[(size_t)u6 * 64 + lane] << 16);
            float x7 = __builtin_bit_cast(float, (u32)g2[(size_t)u7 * 64 + lane] << 16);
            a0 += x0;
            a1 = fmaf(w1, x1, a1);
            a2 = fmaf(w2, x2, a2);
            a3 = fmaf(w3, x3, a3);
            a4 = fmaf(w4, x4, a4);
            a5 = fmaf(w5, x5, a5);
            a6 = fmaf(w6, x6, a6);
            a7 = fmaf(w7, x7, a7);
        }
    }
    float s = ((a0 + a1) + (a2 + a3)) + ((a4 + a5) + (a6 + a7));
    out[(size_t)v * OUTC + lane] = fmaf(dinv[v], s, b2f[lane]);
}

// ---------------- launch ----------------

extern "C" void kernel_launch(void* const* d_in, const int* in_sizes, int n_in,
                              void* d_out, int out_size, void* d_ws, size_t ws_size,
                              hipStream_t stream) {
    const float* x   = (const float*)d_in[0];
    const int*   ei  = (const int*)d_in[1];
    const float* W1  = (const float*)d_in[2];
    const float* b1  = (const float*)d_in[3];
    const float* W2  = (const float*)d_in[4];
    const float* b2  = (const float*)d_in[5];
    const float* Wfc = (const float*)d_in[6];
    const float* bfc = (const float*)d_in[7];
    float* out = (float*)d_out;

    const int n = in_sizes[0] / INC;
    const int E = in_sizes[1] / 2;
    const int* src = ei;
    const int* dst = ei + E;
    const int nb = (n + 1023) / 1024;

    char* w = (char*)d_ws;
    auto alloc = [&](size_t bytes) -> void* {
        void* p = (void*)w;
        w += (bytes + 255) & ~(size_t)255;
        return p;
    };
    int*   cnt    = (int*)alloc((size_t)n * 4);
    int*   fillc  = (int*)alloc((size_t)n * 4);
    int*   rowptr = (int*)alloc((size_t)(n + 1) * 4);
    float* dinvp  = (float*)alloc((size_t)n * 4);
    int*   col    = (int*)alloc((size_t)E * 4);
    u16*   g      = (u16*)alloc((size_t)n * HIDC * 2);   // bf16 g1, reused as g2
    float* h1     = (float*)alloc((size_t)n * HIDC * 4);
    float* W2f    = (float*)alloc((size_t)HIDC * OUTC * 4);
    float* b2f    = (float*)alloc((size_t)OUTC * 4);
    int*   bsum   = (int*)alloc((size_t)nb * 4);
    int*   boff   = (int*)alloc((size_t)nb * 4);

    hipMemsetAsync(cnt, 0, (size_t)n * 4, stream);
    hipMemsetAsync(fillc, 0, (size_t)n * 4, stream);

    fold_kernel<<<(HIDC * OUTC + OUTC + 255) / 256, 256, 0, stream>>>(W2, Wfc, b2, bfc, W2f, b2f);
    hist_kernel<<<(E + 255) / 256, 256, 0, stream>>>(dst, cnt, E);
    dinv_kernel<<<(n + 255) / 256, 256, 0, stream>>>(cnt, dinvp, n);
    scan_part_kernel<<<nb, 256, 0, stream>>>(cnt, bsum, n);
    scan_bsum_kernel<<<1, 1024, 0, stream>>>(bsum, boff, nb);
    scan_final_kernel<<<nb, 256, 0, stream>>>(cnt, boff, rowptr, n, E);
    fill_kernel<<<(E + 255) / 256, 256, 0, stream>>>(src, dst, rowptr, fillc, col, E);

    // layer 1: g = bf16((x @ W1) * dinv) ; h1 = relu(dinv*(g[v]+sum g[u]) + b1)
    gemm_scale_bf16_kernel<64, 128, 32, 4, 8><<<(n + 63) / 64, 256, 0, stream>>>(x, W1, dinvp, g, n);
    agg1_kernel<<<(n + 3) / 4, 256, 0, stream>>>((const u32*)g, rowptr, col, dinvp, b1, h1, n);

    // layer 2 (+FC folded): g2 = bf16((h1 @ W2f) * dinv) ; out = dinv*(g2[v]+sum g2[u]) + b2f
    gemm_scale_bf16_kernel<64, 64, 32, 4, 4><<<(n + 63) / 64, 256, 0, stream>>>(h1, W2f, dinvp, g, n);
    agg2_kernel<<<(n + 3) / 4, 256, 0, stream>>>(g, rowptr, col, dinvp, b2f, out, n);
}

// Round 5
// 273.029 us; speedup vs baseline: 2.8459x; 1.4609x over previous
//
#include <hip/hip_runtime.h>

#define INC  128
#define HIDC 128
#define OUTC 64

#define BSH   8        // bucket = dst >> 8 (256 nodes per bucket)
#define NBMAX 512      // supports n <= 131072
#define HB    128      // bhist blocks
#define TILE  4096     // edges per multisplit block
#define CAP   8192     // csr_build LDS col-stage capacity

typedef unsigned int  u32;
typedef unsigned short u16;

static __device__ __forceinline__ u16 f2bf(float f) {
    u32 u = __builtin_bit_cast(u32, f);
    u += 0x7fffu + ((u >> 16) & 1u);
    return (u16)(u >> 16);
}
static __device__ __forceinline__ float bf_lo(u32 u) {
    return __builtin_bit_cast(float, u << 16);
}
static __device__ __forceinline__ float bf_hi(u32 u) {
    return __builtin_bit_cast(float, u & 0xffff0000u);
}

// ---------------- CSR build: bucket hist -> scan -> multisplit -> per-bucket CSR ----

__global__ __launch_bounds__(256) void bhist_kernel(const int* __restrict__ dst,
                                                    int* __restrict__ parts,  // [NBMAX][HB] (transposed)
                                                    int E, int nb) {
    __shared__ int h[NBMAX];
    for (int i = threadIdx.x; i < NBMAX; i += 256) h[i] = 0;
    __syncthreads();
    const int total = HB * 256;
    for (int e = blockIdx.x * 256 + threadIdx.x; e < E; e += total)
        atomicAdd(&h[dst[e] >> BSH], 1);
    __syncthreads();
    for (int i = threadIdx.x; i < nb; i += 256) parts[i * HB + blockIdx.x] = h[i];
}

// single block: per-bucket reduce + exclusive scan -> bucketOff[0..nb]
__global__ __launch_bounds__(512) void bscan_kernel(const int* __restrict__ parts,
                                                    int* __restrict__ bucketOff, int nb) {
    __shared__ int sums[NBMAX];
    const int tid = threadIdx.x;
    int s = 0;
    if (tid < nb) {
        const int* p = parts + tid * HB;
#pragma unroll 8
        for (int r = 0; r < HB; ++r) s += p[r];
    }
    sums[tid] = s;
    __syncthreads();
    for (int d = 1; d < NBMAX; d <<= 1) {
        int t = sums[tid];
        int a = (tid >= d) ? sums[tid - d] : 0;
        __syncthreads();
        sums[tid] = t + a;
        __syncthreads();
    }
    if (tid < nb) bucketOff[tid] = sums[tid] - s;
    if (tid == NBMAX - 1) bucketOff[nb] = sums[NBMAX - 1];
}

// one block per TILE edges: LDS multisplit into nb buckets, contiguous run writes
__global__ __launch_bounds__(256) void multisplit_kernel(const int* __restrict__ src,
                                                         const int* __restrict__ dst,
                                                         const int* __restrict__ bucketOff,
                                                         int* __restrict__ gfill,   // [nb] zeroed
                                                         int2* __restrict__ binned, // [E]
                                                         int E, int nb) {
    __shared__ int hist[NBMAX];
    __shared__ int sbase[NBMAX];
    __shared__ int cursor[NBMAX];
    __shared__ int gposs[NBMAX];
    __shared__ int wsum[4];
    __shared__ int2 buf[TILE];
    const int tid  = threadIdx.x;
    const int base = blockIdx.x * TILE;
    const int cnt  = min(TILE, E - base);

    for (int i = tid; i < NBMAX; i += 256) hist[i] = 0;
    __syncthreads();

    int ls[16], ld[16], dg[16];
#pragma unroll
    for (int k = 0; k < 16; ++k) {
        int idx = tid + k * 256;
        if (idx < cnt) {
            ls[k] = src[base + idx];
            ld[k] = dst[base + idx];
            dg[k] = ld[k] >> BSH;
            atomicAdd(&hist[dg[k]], 1);
        } else dg[k] = -1;
    }
    __syncthreads();
    // exclusive scan of hist[0..NBMAX): thread t owns slots 2t, 2t+1
    {
        const int a = hist[2 * tid], b = hist[2 * tid + 1];
        const int s = a + b;
        const int lane = tid & 63;
        int incl = s;
#pragma unroll
        for (int d = 1; d < 64; d <<= 1) {
            int t = __shfl_up(incl, d);
            if (lane >= d) incl += t;
        }
        if (lane == 63) wsum[tid >> 6] = incl;
        __syncthreads();
        const int w = tid >> 6;
        int wbase = 0;
        if (w > 0) wbase += wsum[0];
        if (w > 1) wbase += wsum[1];
        if (w > 2) wbase += wsum[2];
        const int excl = wbase + incl - s;
        sbase[2 * tid] = excl;          cursor[2 * tid] = excl;
        sbase[2 * tid + 1] = excl + a;  cursor[2 * tid + 1] = excl + a;
    }
    __syncthreads();
    // scatter tile into LDS grouped by bucket
#pragma unroll
    for (int k = 0; k < 16; ++k) {
        if (dg[k] >= 0) {
            int p = atomicAdd(&cursor[dg[k]], 1);
            buf[p] = make_int2(ls[k], ld[k]);
        }
    }
    __syncthreads();
    // one global claim per non-empty bucket
    for (int d = tid; d < nb; d += 256) {
        int c = cursor[d] - sbase[d];
        gposs[d] = (c > 0) ? atomicAdd(&gfill[d], c) : 0;
    }
    __syncthreads();
    // contiguous run writes
    for (int idx = tid; idx < cnt; idx += 256) {
        int2 e = buf[idx];
        int d = e.y >> BSH;
        binned[bucketOff[d] + gposs[d] + (idx - sbase[d])] = e;
    }
}

// one block per bucket: per-node counts + scan in LDS, coalesced col/rowptr/dinv
__global__ __launch_bounds__(256) void csr_build_kernel(const int2* __restrict__ binned,
                                                        const int* __restrict__ bucketOff,
                                                        int* __restrict__ col,
                                                        int* __restrict__ rowptr,
                                                        float* __restrict__ dinv,
                                                        int n, int E) {
    __shared__ int cnt[257];
    __shared__ int excl[256];
    __shared__ int wsum[4];
    __shared__ int colstage[CAP];
    const int tid   = threadIdx.x;
    const int b     = blockIdx.x;
    const int node0 = b << BSH;
    const int nNodes = min(256, n - node0);
    const int e0 = bucketOff[b], e1 = bucketOff[b + 1];
    const int ec = e1 - e0;

    for (int i = tid; i <= 256; i += 256) cnt[i] = 0;
    __syncthreads();
    for (int i = tid; i < ec; i += 256)
        atomicAdd(&cnt[binned[e0 + i].y & 255], 1);
    __syncthreads();
    const int myc = cnt[tid];
    // exclusive scan of cnt[0..256)
    {
        const int lane = tid & 63;
        int incl = myc;
#pragma unroll
        for (int d = 1; d < 64; d <<= 1) {
            int t = __shfl_up(incl, d);
            if (lane >= d) incl += t;
        }
        if (lane == 63) wsum[tid >> 6] = incl;
        __syncthreads();
        const int w = tid >> 6;
        int wbase = 0;
        if (w > 0) wbase += wsum[0];
        if (w > 1) wbase += wsum[1];
        if (w > 2) wbase += wsum[2];
        excl[tid] = wbase + incl - myc;
    }
    __syncthreads();
    if (tid < nNodes) {
        const int node = node0 + tid;
        rowptr[node] = e0 + excl[tid];
        dinv[node] = rsqrtf((float)(myc + 1));
    }
    if (b == 0 && tid == 0) rowptr[n] = E;
    __syncthreads();
    cnt[tid] = excl[tid];  // reuse as cursor
    __syncthreads();
    if (ec <= CAP) {
        for (int i = tid; i < ec; i += 256) {
            int2 e = binned[e0 + i];
            int p = atomicAdd(&cnt[e.y & 255], 1);
            colstage[p] = e.x;
        }
        __syncthreads();
        for (int i = tid; i < ec; i += 256) col[e0 + i] = colstage[i];
    } else {  // safety fallback (never triggers for this input)
        for (int i = tid; i < ec; i += 256) {
            int2 e = binned[e0 + i];
            int p = atomicAdd(&cnt[e.y & 255], 1);
            col[e0 + p] = e.x;
        }
    }
}

// fold FC into layer-2 weights: W2f = W2 @ Wfc  [128x64], b2f = b2 @ Wfc + bfc [64]
__global__ __launch_bounds__(256) void fold_kernel(const float* __restrict__ W2,
                                                   const float* __restrict__ Wfc,
                                                   const float* __restrict__ b2,
                                                   const float* __restrict__ bfc,
                                                   float* __restrict__ W2f,
                                                   float* __restrict__ b2f) {
    int t = blockIdx.x * 256 + threadIdx.x;
    if (t < HIDC * OUTC) {
        int i = t >> 6, j = t & 63;
        float s = 0.f;
#pragma unroll 8
        for (int k = 0; k < OUTC; ++k) s = fmaf(W2[i * OUTC + k], Wfc[k * OUTC + j], s);
        W2f[t] = s;
    } else if (t < HIDC * OUTC + OUTC) {
        int j = t - HIDC * OUTC;
        float s = bfc[j];
#pragma unroll 8
        for (int k = 0; k < OUTC; ++k) s = fmaf(b2[k], Wfc[k * OUTC + j], s);
        b2f[j] = s;
    }
}

// ---------------- fp32 tiled GEMM -> bf16 output, epilogue scales row by dinv ----

template <int BM, int BN, int BK, int TM, int TN>
__global__ __launch_bounds__(256) void gemm_scale_bf16_kernel(const float* __restrict__ A,
                                                              const float* __restrict__ W,
                                                              const float* __restrict__ dinv,
                                                              u16* __restrict__ out, int M) {
    static_assert(TM == 4, "A fragment read assumes float4");
    constexpr int K   = 128;
    constexpr int LDA = BM + 4;
    constexpr int LDB = BN + 4;
    __shared__ __align__(16) float As[BK][LDA];   // transposed: As[k][r]
    __shared__ __align__(16) float Ws[BK][LDB];

    const int tid  = threadIdx.x;
    const int row0 = blockIdx.x * BM;
    constexpr int NTC = BN / TN;
    const int tr = tid / NTC;
    const int tc = tid % NTC;

    float acc[TM][TN];
#pragma unroll
    for (int m = 0; m < TM; ++m)
#pragma unroll
        for (int n = 0; n < TN; ++n) acc[m][n] = 0.f;

    for (int k0 = 0; k0 < K; k0 += BK) {
#pragma unroll
        for (int i = tid; i < BM * BK / 4; i += 256) {
            int r  = i / (BK / 4);
            int c4 = (i % (BK / 4)) * 4;
            float4 v = make_float4(0.f, 0.f, 0.f, 0.f);
            int grow = row0 + r;
            if (grow < M) v = *(const float4*)&A[(size_t)grow * K + k0 + c4];
            As[c4 + 0][r] = v.x; As[c4 + 1][r] = v.y;
            As[c4 + 2][r] = v.z; As[c4 + 3][r] = v.w;
        }
#pragma unroll
        for (int i = tid; i < BK * BN / 4; i += 256) {
            int kk = i / (BN / 4);
            int c4 = (i % (BN / 4)) * 4;
            *(float4*)&Ws[kk][c4] = *(const float4*)&W[(size_t)(k0 + kk) * BN + c4];
        }
        __syncthreads();
#pragma unroll
        for (int k = 0; k < BK; ++k) {
            float a[TM], b[TN];
            *(float4*)&a[0] = *(const float4*)&As[k][tr * TM];
#pragma unroll
            for (int n4 = 0; n4 < TN; n4 += 4)
                *(float4*)&b[n4] = *(const float4*)&Ws[k][tc * TN + n4];
#pragma unroll
            for (int m = 0; m < TM; ++m)
#pragma unroll
                for (int n = 0; n < TN; ++n)
                    acc[m][n] = fmaf(a[m], b[n], acc[m][n]);
        }
        __syncthreads();
    }
#pragma unroll
    for (int m = 0; m < TM; ++m) {
        int grow = row0 + tr * TM + m;
        if (grow < M) {
            float sc = dinv[grow];
            u32 p[TN / 2];
#pragma unroll
            for (int j = 0; j < TN / 2; ++j)
                p[j] = (u32)f2bf(acc[m][2 * j] * sc) | ((u32)f2bf(acc[m][2 * j + 1] * sc) << 16);
            u32* dstp = (u32*)(out + (size_t)grow * BN + tc * TN);
            if constexpr (TN == 8)      *(uint4*)dstp = *(uint4*)p;
            else if constexpr (TN == 4) *(uint2*)dstp = *(uint2*)p;
            else                        *dstp = p[0];
        }
    }
}

// ---------------- aggregation: one wave per node, shfl-broadcast indices,
// ---------------- 8-wide unrolled bf16 gathers ----------------------------

__global__ __launch_bounds__(256) void agg1_kernel(const u32* __restrict__ g,   // bf16x2 words
                                                   const int* __restrict__ rowptr,
                                                   const int* __restrict__ col,
                                                   const float* __restrict__ dinv,
                                                   const float* __restrict__ b1,
                                                   float* __restrict__ h1, int n) {
    const int wid  = threadIdx.x >> 6;
    const int lane = threadIdx.x & 63;
    const int v = blockIdx.x * 4 + wid;
    if (v >= n) return;
    const int base = rowptr[v], endi = rowptr[v + 1];

    u32 uv = g[(size_t)v * 64 + lane];
    float a0x = bf_lo(uv), a0y = bf_hi(uv);
    float a1x = 0.f, a1y = 0.f, a2x = 0.f, a2y = 0.f, a3x = 0.f, a3y = 0.f;
    float a4x = 0.f, a4y = 0.f, a5x = 0.f, a5y = 0.f, a6x = 0.f, a6y = 0.f, a7x = 0.f, a7y = 0.f;

    for (int c = base; c < endi; c += 64) {
        const int m = min(64, endi - c);
        const int idx = col[c + min(lane, m - 1)];
        for (int i = 0; i < m; i += 8) {
            int u0 = __shfl(idx, i);
            int u1 = __shfl(idx, min(i + 1, m - 1));
            int u2 = __shfl(idx, min(i + 2, m - 1));
            int u3 = __shfl(idx, min(i + 3, m - 1));
            int u4 = __shfl(idx, min(i + 4, m - 1));
            int u5 = __shfl(idx, min(i + 5, m - 1));
            int u6 = __shfl(idx, min(i + 6, m - 1));
            int u7 = __shfl(idx, min(i + 7, m - 1));
            float w1 = (i + 1 < m) ? 1.f : 0.f;
            float w2 = (i + 2 < m) ? 1.f : 0.f;
            float w3 = (i + 3 < m) ? 1.f : 0.f;
            float w4 = (i + 4 < m) ? 1.f : 0.f;
            float w5 = (i + 5 < m) ? 1.f : 0.f;
            float w6 = (i + 6 < m) ? 1.f : 0.f;
            float w7 = (i + 7 < m) ? 1.f : 0.f;
            u32 x0 = g[(size_t)u0 * 64 + lane];
            u32 x1 = g[(size_t)u1 * 64 + lane];
            u32 x2 = g[(size_t)u2 * 64 + lane];
            u32 x3 = g[(size_t)u3 * 64 + lane];
            u32 x4 = g[(size_t)u4 * 64 + lane];
            u32 x5 = g[(size_t)u5 * 64 + lane];
            u32 x6 = g[(size_t)u6 * 64 + lane];
            u32 x7 = g[(size_t)u7 * 64 + lane];
            a0x += bf_lo(x0);                a0y += bf_hi(x0);
            a1x = fmaf(w1, bf_lo(x1), a1x);  a1y = fmaf(w1, bf_hi(x1), a1y);
            a2x = fmaf(w2, bf_lo(x2), a2x);  a2y = fmaf(w2, bf_hi(x2), a2y);
            a3x = fmaf(w3, bf_lo(x3), a3x);  a3y = fmaf(w3, bf_hi(x3), a3y);
            a4x = fmaf(w4, bf_lo(x4), a4x);  a4y = fmaf(w4, bf_hi(x4), a4y);
            a5x = fmaf(w5, bf_lo(x5), a5x);  a5y = fmaf(w5, bf_hi(x5), a5y);
            a6x = fmaf(w6, bf_lo(x6), a6x);  a6y = fmaf(w6, bf_hi(x6), a6y);
            a7x = fmaf(w7, bf_lo(x7), a7x);  a7y = fmaf(w7, bf_hi(x7), a7y);
        }
    }
    float sx = ((a0x + a1x) + (a2x + a3x)) + ((a4x + a5x) + (a6x + a7x));
    float sy = ((a0y + a1y) + (a2y + a3y)) + ((a4y + a5y) + (a6y + a7y));
    const float dv = dinv[v];
    const float2 bb = *(const float2*)&b1[lane * 2];
    float o0 = fmaxf(fmaf(dv, sx, bb.x), 0.f);
    float o1 = fmaxf(fmaf(dv, sy, bb.y), 0.f);
    *(float2*)&h1[(size_t)v * HIDC + (size_t)lane * 2] = make_float2(o0, o1);
}

__global__ __launch_bounds__(256) void agg2_kernel(const u16* __restrict__ g2,
                                                   const int* __restrict__ rowptr,
                                                   const int* __restrict__ col,
                                                   const float* __restrict__ dinv,
                                                   const float* __restrict__ b2f,
                                                   float* __restrict__ out, int n) {
    const int wid  = threadIdx.x >> 6;
    const int lane = threadIdx.x & 63;
    const int v = blockIdx.x * 4 + wid;
    if (v >= n) return;
    const int base = rowptr[v], endi = rowptr[v + 1];

    float a0 = __builtin_bit_cast(float, (u32)g2[(size_t)v * 64 + lane] << 16);
    float a1 = 0.f, a2 = 0.f, a3 = 0.f, a4 = 0.f, a5 = 0.f, a6 = 0.f, a7 = 0.f;

    for (int c = base; c < endi; c += 64) {
        const int m = min(64, endi - c);
        const int idx = col[c + min(lane, m - 1)];
        for (int i = 0; i < m; i += 8) {
            int u0 = __shfl(idx, i);
            int u1 = __shfl(idx, min(i + 1, m - 1));
            int u2 = __shfl(idx, min(i + 2, m - 1));
            int u3 = __shfl(idx, min(i + 3, m - 1));
            int u4 = __shfl(idx, min(i + 4, m - 1));
            int u5 = __shfl(idx, min(i + 5, m - 1));
            int u6 = __shfl(idx, min(i + 6, m - 1));
            int u7 = __shfl(idx, min(i + 7, m - 1));
            float w1 = (i + 1 < m) ? 1.f : 0.f;
            float w2 = (i + 2 < m) ? 1.f : 0.f;
            float w3 = (i + 3 < m) ? 1.f : 0.f;
            float w4 = (i + 4 < m) ? 1.f : 0.f;
            float w5 = (i + 5 < m) ? 1.f : 0.f;
            float w6 = (i + 6 < m) ? 1.f : 0.f;
            float w7 = (i + 7 < m) ? 1.f : 0.f;
            float x0 = __builtin_bit_cast(float, (u32)g2[(size_t)u0 * 64 + lane] << 16);
            float x1 = __builtin_bit_cast(float, (u32)g2[(size_t)u1 * 64 + lane] << 16);
            float x2 = __builtin_bit_cast(float, (u32)g2[(size_t)u2 * 64 + lane] << 16);
            float x3 = __builtin_bit_cast(float, (u32)g2[(size_t)u3 * 64 + lane] << 16);
            float x4 = __builtin_bit_cast(float, (u32)g2[(size_t)u4 * 64 + lane] << 16);
            float x5 = __builtin_bit_cast(float, (u32)g2[(size_t)u5 * 64 + lane] << 16);
            float x6 = __builtin_bit_cast(float, (u32)g2[(size_t)u6 * 64 + lane] << 16);
            float x7 = __builtin_bit_cast(float, (u32)g2[(size_t)u7 * 64 + lane] << 16);
            a0 += x0;
            a1 = fmaf(w1, x1, a1);
            a2 = fmaf(w2, x2, a2);
            a3 = fmaf(w3, x3, a3);
            a4 = fmaf(w4, x4, a4);
            a5 = fmaf(w5, x5, a5);
            a6 = fmaf(w6, x6, a6);
            a7 = fmaf(w7, x7, a7);
        }
    }
    float s = ((a0 + a1) + (a2 + a3)) + ((a4 + a5) + (a6 + a7));
    out[(size_t)v * OUTC + lane] = fmaf(dinv[v], s, b2f[lane]);
}

// ---------------- launch ----------------

extern "C" void kernel_launch(void* const* d_in, const int* in_sizes, int n_in,
                              void* d_out, int out_size, void* d_ws, size_t ws_size,
                              hipStream_t stream) {
    const float* x   = (const float*)d_in[0];
    const int*   ei  = (const int*)d_in[1];
    const float* W1  = (const float*)d_in[2];
    const float* b1  = (const float*)d_in[3];
    const float* W2  = (const float*)d_in[4];
    const float* b2  = (const float*)d_in[5];
    const float* Wfc = (const float*)d_in[6];
    const float* bfc = (const float*)d_in[7];
    float* out = (float*)d_out;

    const int n = in_sizes[0] / INC;
    const int E = in_sizes[1] / 2;
    const int* src = ei;
    const int* dst = ei + E;
    const int nb = (n + 255) >> BSH;

    char* w = (char*)d_ws;
    auto alloc = [&](size_t bytes) -> void* {
        void* p = (void*)w;
        w += (bytes + 255) & ~(size_t)255;
        return p;
    };
    int*   rowptr    = (int*)alloc((size_t)(n + 1) * 4);
    float* dinvp     = (float*)alloc((size_t)n * 4);
    int*   col       = (int*)alloc((size_t)E * 4);
    int2*  binned    = (int2*)alloc((size_t)E * 8);
    int*   parts     = (int*)alloc((size_t)NBMAX * HB * 4);
    int*   bucketOff = (int*)alloc((size_t)(nb + 1) * 4);
    int*   gfill     = (int*)alloc((size_t)nb * 4);
    u16*   g         = (u16*)alloc((size_t)n * HIDC * 2);   // bf16 g1, reused as g2
    float* h1        = (float*)alloc((size_t)n * HIDC * 4);
    float* W2f       = (float*)alloc((size_t)HIDC * OUTC * 4);
    float* b2f       = (float*)alloc((size_t)OUTC * 4);

    hipMemsetAsync(gfill, 0, (size_t)nb * 4, stream);

    fold_kernel<<<(HIDC * OUTC + OUTC + 255) / 256, 256, 0, stream>>>(W2, Wfc, b2, bfc, W2f, b2f);
    bhist_kernel<<<HB, 256, 0, stream>>>(dst, parts, E, nb);
    bscan_kernel<<<1, NBMAX, 0, stream>>>(parts, bucketOff, nb);
    multisplit_kernel<<<(E + TILE - 1) / TILE, 256, 0, stream>>>(src, dst, bucketOff, gfill, binned, E, nb);
    csr_build_kernel<<<nb, 256, 0, stream>>>(binned, bucketOff, col, rowptr, dinvp, n, E);

    // layer 1: g = bf16((x @ W1) * dinv) ; h1 = relu(dinv*(g[v]+sum g[u]) + b1)
    gemm_scale_bf16_kernel<64, 128, 32, 4, 8><<<(n + 63) / 64, 256, 0, stream>>>(x, W1, dinvp, g, n);
    agg1_kernel<<<(n + 3) / 4, 256, 0, stream>>>((const u32*)g, rowptr, col, dinvp, b1, h1, n);

    // layer 2 (+FC folded): g2 = bf16((h1 @ W2f) * dinv) ; out = dinv*(g2[v]+sum g2[u]) + b2f
    gemm_scale_bf16_kernel<64, 64, 32, 4, 4><<<(n + 63) / 64, 256, 0, stream>>>(h1, W2f, dinvp, g, n);
    agg2_kernel<<<(n + 3) / 4, 256, 0, stream>>>(g, rowptr, col, dinvp, b2f, out, n);
}

// Round 6
// 205.931 us; speedup vs baseline: 3.7732x; 1.3258x over previous
//
#include <hip/hip_runtime.h>

#define INC  128
#define HIDC 128
#define OUTC 64

#define BSH   8        // bucket = dst >> 8 (256 nodes per bucket)
#define NBMAX 512      // supports n <= 131072
#define HB    128      // bhist blocks
#define TILE  4096     // edges per multisplit block
#define CAP   8192     // csr_build LDS col-stage capacity

typedef unsigned int  u32;
typedef unsigned short u16;
typedef short bf16x8 __attribute__((ext_vector_type(8)));
typedef float f32x4 __attribute__((ext_vector_type(4)));

static __device__ __forceinline__ u16 f2bf(float f) {
    u32 u = __builtin_bit_cast(u32, f);
    u += 0x7fffu + ((u >> 16) & 1u);
    return (u16)(u >> 16);
}
static __device__ __forceinline__ float bf_lo(u32 u) {
    return __builtin_bit_cast(float, u << 16);
}
static __device__ __forceinline__ float bf_hi(u32 u) {
    return __builtin_bit_cast(float, u & 0xffff0000u);
}

// ---------------- CSR build: bucket hist -> scan -> multisplit -> per-bucket CSR ----

__global__ __launch_bounds__(256) void bhist_kernel(const int* __restrict__ dst,
                                                    int* __restrict__ parts,  // [NBMAX][HB]
                                                    int E, int nb) {
    __shared__ int h[NBMAX];
    for (int i = threadIdx.x; i < NBMAX; i += 256) h[i] = 0;
    __syncthreads();
    const int total = HB * 256;
    for (int e = blockIdx.x * 256 + threadIdx.x; e < E; e += total)
        atomicAdd(&h[dst[e] >> BSH], 1);
    __syncthreads();
    for (int i = threadIdx.x; i < nb; i += 256) parts[i * HB + blockIdx.x] = h[i];
}

__global__ __launch_bounds__(512) void bscan_kernel(const int* __restrict__ parts,
                                                    int* __restrict__ bucketOff, int nb) {
    __shared__ int sums[NBMAX];
    const int tid = threadIdx.x;
    int s = 0;
    if (tid < nb) {
        const int* p = parts + tid * HB;
#pragma unroll 8
        for (int r = 0; r < HB; ++r) s += p[r];
    }
    sums[tid] = s;
    __syncthreads();
    for (int d = 1; d < NBMAX; d <<= 1) {
        int t = sums[tid];
        int a = (tid >= d) ? sums[tid - d] : 0;
        __syncthreads();
        sums[tid] = t + a;
        __syncthreads();
    }
    if (tid < nb) bucketOff[tid] = sums[tid] - s;
    if (tid == NBMAX - 1) bucketOff[nb] = sums[NBMAX - 1];
}

__global__ __launch_bounds__(256) void multisplit_kernel(const int* __restrict__ src,
                                                         const int* __restrict__ dst,
                                                         const int* __restrict__ bucketOff,
                                                         int* __restrict__ gfill,
                                                         int2* __restrict__ binned,
                                                         int E, int nb) {
    __shared__ int hist[NBMAX];
    __shared__ int sbase[NBMAX];
    __shared__ int cursor[NBMAX];
    __shared__ int gposs[NBMAX];
    __shared__ int wsum[4];
    __shared__ int2 buf[TILE];
    const int tid  = threadIdx.x;
    const int base = blockIdx.x * TILE;
    const int cnt  = min(TILE, E - base);

    for (int i = tid; i < NBMAX; i += 256) hist[i] = 0;
    __syncthreads();

    int ls[16], ld[16], dg[16];
#pragma unroll
    for (int k = 0; k < 16; ++k) {
        int idx = tid + k * 256;
        if (idx < cnt) {
            ls[k] = src[base + idx];
            ld[k] = dst[base + idx];
            dg[k] = ld[k] >> BSH;
            atomicAdd(&hist[dg[k]], 1);
        } else dg[k] = -1;
    }
    __syncthreads();
    {
        const int a = hist[2 * tid], b = hist[2 * tid + 1];
        const int s = a + b;
        const int lane = tid & 63;
        int incl = s;
#pragma unroll
        for (int d = 1; d < 64; d <<= 1) {
            int t = __shfl_up(incl, d);
            if (lane >= d) incl += t;
        }
        if (lane == 63) wsum[tid >> 6] = incl;
        __syncthreads();
        const int w = tid >> 6;
        int wbase = 0;
        if (w > 0) wbase += wsum[0];
        if (w > 1) wbase += wsum[1];
        if (w > 2) wbase += wsum[2];
        const int excl = wbase + incl - s;
        sbase[2 * tid] = excl;          cursor[2 * tid] = excl;
        sbase[2 * tid + 1] = excl + a;  cursor[2 * tid + 1] = excl + a;
    }
    __syncthreads();
#pragma unroll
    for (int k = 0; k < 16; ++k) {
        if (dg[k] >= 0) {
            int p = atomicAdd(&cursor[dg[k]], 1);
            buf[p] = make_int2(ls[k], ld[k]);
        }
    }
    __syncthreads();
    for (int d = tid; d < nb; d += 256) {
        int c = cursor[d] - sbase[d];
        gposs[d] = (c > 0) ? atomicAdd(&gfill[d], c) : 0;
    }
    __syncthreads();
    for (int idx = tid; idx < cnt; idx += 256) {
        int2 e = buf[idx];
        int d = e.y >> BSH;
        binned[bucketOff[d] + gposs[d] + (idx - sbase[d])] = e;
    }
}

__global__ __launch_bounds__(256) void csr_build_kernel(const int2* __restrict__ binned,
                                                        const int* __restrict__ bucketOff,
                                                        int* __restrict__ col,
                                                        int* __restrict__ rowptr,
                                                        float* __restrict__ dinv,
                                                        int n, int E) {
    __shared__ int cnt[257];
    __shared__ int excl[256];
    __shared__ int wsum[4];
    __shared__ int colstage[CAP];
    const int tid   = threadIdx.x;
    const int b     = blockIdx.x;
    const int node0 = b << BSH;
    const int nNodes = min(256, n - node0);
    const int e0 = bucketOff[b], e1 = bucketOff[b + 1];
    const int ec = e1 - e0;

    for (int i = tid; i <= 256; i += 256) cnt[i] = 0;
    __syncthreads();
    for (int i = tid; i < ec; i += 256)
        atomicAdd(&cnt[binned[e0 + i].y & 255], 1);
    __syncthreads();
    const int myc = cnt[tid];
    {
        const int lane = tid & 63;
        int incl = myc;
#pragma unroll
        for (int d = 1; d < 64; d <<= 1) {
            int t = __shfl_up(incl, d);
            if (lane >= d) incl += t;
        }
        if (lane == 63) wsum[tid >> 6] = incl;
        __syncthreads();
        const int w = tid >> 6;
        int wbase = 0;
        if (w > 0) wbase += wsum[0];
        if (w > 1) wbase += wsum[1];
        if (w > 2) wbase += wsum[2];
        excl[tid] = wbase + incl - myc;
    }
    __syncthreads();
    if (tid < nNodes) {
        const int node = node0 + tid;
        rowptr[node] = e0 + excl[tid];
        dinv[node] = rsqrtf((float)(myc + 1));
    }
    if (b == 0 && tid == 0) rowptr[n] = E;
    __syncthreads();
    cnt[tid] = excl[tid];
    __syncthreads();
    if (ec <= CAP) {
        for (int i = tid; i < ec; i += 256) {
            int2 e = binned[e0 + i];
            int p = atomicAdd(&cnt[e.y & 255], 1);
            colstage[p] = e.x;
        }
        __syncthreads();
        for (int i = tid; i < ec; i += 256) col[e0 + i] = colstage[i];
    } else {
        for (int i = tid; i < ec; i += 256) {
            int2 e = binned[e0 + i];
            int p = atomicAdd(&cnt[e.y & 255], 1);
            col[e0 + p] = e.x;
        }
    }
}

// fold + convert: W1t_bf[n][k] = bf16(W1[k][n]); W2ft_bf[j][i] = bf16(sum_k W2[i][k]Wfc[k][j]);
// b2f = b2 @ Wfc + bfc (f32)
__global__ __launch_bounds__(256) void fold_kernel(const float* __restrict__ W1,
                                                   const float* __restrict__ W2,
                                                   const float* __restrict__ Wfc,
                                                   const float* __restrict__ b2,
                                                   const float* __restrict__ bfc,
                                                   u16* __restrict__ W1t,
                                                   u16* __restrict__ W2ft,
                                                   float* __restrict__ b2f) {
    int t = blockIdx.x * 256 + threadIdx.x;
    if (t < HIDC * HIDC) {                       // W1 transpose->bf16
        int nn = t >> 7, k = t & 127;
        W1t[nn * HIDC + k] = f2bf(W1[k * HIDC + nn]);
    } else if (t < HIDC * HIDC + HIDC * OUTC) {  // W2f fold, transposed bf16
        int u = t - HIDC * HIDC;
        int i = u >> 6, j = u & 63;
        float s = 0.f;
#pragma unroll 8
        for (int k = 0; k < OUTC; ++k) s = fmaf(W2[i * OUTC + k], Wfc[k * OUTC + j], s);
        W2ft[j * HIDC + i] = f2bf(s);
    } else if (t < HIDC * HIDC + HIDC * OUTC + OUTC) {
        int j = t - HIDC * HIDC - HIDC * OUTC;
        float s = bfc[j];
#pragma unroll 8
        for (int k = 0; k < OUTC; ++k) s = fmaf(b2[k], Wfc[k * OUTC + j], s);
        b2f[j] = s;
    }
}

// ---------------- MFMA bf16 GEMM: [M,128] @ [128,N] -> bf16 out scaled by dinv ----
// K=128 in one pass. W supplied pre-transposed bf16 [N][128]. A-fragments loaded
// straight from global (lane = row lane&15, k-chunk (lane>>4)*8 contiguous 16/32B).
// LDS W tile XOR-swizzled (slot ^= n&7) to kill stride-256B bank conflicts.

template <int N, bool AF32>
__global__ __launch_bounds__(256) void mfma_gemm_kernel(const void* __restrict__ Aptr,
                                                        const u16* __restrict__ Wt,
                                                        const float* __restrict__ dinv,
                                                        u16* __restrict__ out, int M) {
    constexpr int K = 128;
    constexpr int NC = N / 16;
    __shared__ u16 Ws[N * K];   // 16B slots: slot = n*16 + (c ^ (n&7))

    const int tid = threadIdx.x;
    for (int id = tid; id < N * K / 8; id += 256) {
        int nn = id >> 4;
        int c  = id & 15;
        uint4 v = *(const uint4*)(Wt + nn * K + c * 8);
        int slot = (nn << 4) + (c ^ (nn & 7));
        *(uint4*)((char*)Ws + slot * 16) = v;
    }

    const int wave = tid >> 6;
    const int lane = tid & 63;
    const int r0   = blockIdx.x * 64 + wave * 16;
    const int arow = r0 + (lane & 15);
    const int kgrp = lane >> 4;   // 0..3
    __syncthreads();

    f32x4 acc[NC];
#pragma unroll
    for (int nc = 0; nc < NC; ++nc) acc[nc] = f32x4{0.f, 0.f, 0.f, 0.f};

#pragma unroll
    for (int kc = 0; kc < 4; ++kc) {
        bf16x8 af = {0, 0, 0, 0, 0, 0, 0, 0};
        if (arow < M) {
            if constexpr (AF32) {
                const float* ap = (const float*)Aptr + (size_t)arow * K + kc * 32 + kgrp * 8;
                float4 v0 = *(const float4*)ap;
                float4 v1 = *(const float4*)(ap + 4);
                af[0] = (short)f2bf(v0.x); af[1] = (short)f2bf(v0.y);
                af[2] = (short)f2bf(v0.z); af[3] = (short)f2bf(v0.w);
                af[4] = (short)f2bf(v1.x); af[5] = (short)f2bf(v1.y);
                af[6] = (short)f2bf(v1.z); af[7] = (short)f2bf(v1.w);
            } else {
                af = *(const bf16x8*)((const u16*)Aptr + (size_t)arow * K + kc * 32 + kgrp * 8);
            }
        }
#pragma unroll
        for (int nc = 0; nc < NC; ++nc) {
            int nn = nc * 16 + (lane & 15);
            int slot = (nn << 4) + ((kc * 4 + kgrp) ^ (nn & 7));
            bf16x8 bfr = *(const bf16x8*)((const char*)Ws + slot * 16);
            acc[nc] = __builtin_amdgcn_mfma_f32_16x16x32_bf16(af, bfr, acc[nc], 0, 0, 0);
        }
    }
    // C/D: col = lane&15, row = (lane>>4)*4 + reg  [measured m89]
#pragma unroll
    for (int reg = 0; reg < 4; ++reg) {
        int row = r0 + (lane >> 4) * 4 + reg;
        if (row < M) {
            float sc = dinv[row];
#pragma unroll
            for (int nc = 0; nc < NC; ++nc)
                out[(size_t)row * N + nc * 16 + (lane & 15)] = f2bf(acc[nc][reg] * sc);
        }
    }
}

// ---------------- aggregation: one wave per node, shfl-broadcast indices,
// ---------------- 8-wide unrolled bf16 gathers ----------------------------

// h1[v] = bf16(relu(dinv[v] * (g[v] + sum g[u]) + b1))  ; 2 ch/lane
__global__ __launch_bounds__(256) void agg1_kernel(const u32* __restrict__ g,   // bf16x2 words
                                                   const int* __restrict__ rowptr,
                                                   const int* __restrict__ col,
                                                   const float* __restrict__ dinv,
                                                   const float* __restrict__ b1,
                                                   u32* __restrict__ h1, int n) {  // bf16x2 words
    const int wid  = threadIdx.x >> 6;
    const int lane = threadIdx.x & 63;
    const int v = blockIdx.x * 4 + wid;
    if (v >= n) return;
    const int base = rowptr[v], endi = rowptr[v + 1];

    u32 uv = g[(size_t)v * 64 + lane];
    float a0x = bf_lo(uv), a0y = bf_hi(uv);
    float a1x = 0.f, a1y = 0.f, a2x = 0.f, a2y = 0.f, a3x = 0.f, a3y = 0.f;
    float a4x = 0.f, a4y = 0.f, a5x = 0.f, a5y = 0.f, a6x = 0.f, a6y = 0.f, a7x = 0.f, a7y = 0.f;

    for (int c = base; c < endi; c += 64) {
        const int m = min(64, endi - c);
        const int idx = col[c + min(lane, m - 1)];
        for (int i = 0; i < m; i += 8) {
            int u0 = __shfl(idx, i);
            int u1 = __shfl(idx, min(i + 1, m - 1));
            int u2 = __shfl(idx, min(i + 2, m - 1));
            int u3 = __shfl(idx, min(i + 3, m - 1));
            int u4 = __shfl(idx, min(i + 4, m - 1));
            int u5 = __shfl(idx, min(i + 5, m - 1));
            int u6 = __shfl(idx, min(i + 6, m - 1));
            int u7 = __shfl(idx, min(i + 7, m - 1));
            float w1 = (i + 1 < m) ? 1.f : 0.f;
            float w2 = (i + 2 < m) ? 1.f : 0.f;
            float w3 = (i + 3 < m) ? 1.f : 0.f;
            float w4 = (i + 4 < m) ? 1.f : 0.f;
            float w5 = (i + 5 < m) ? 1.f : 0.f;
            float w6 = (i + 6 < m) ? 1.f : 0.f;
            float w7 = (i + 7 < m) ? 1.f : 0.f;
            u32 x0 = g[(size_t)u0 * 64 + lane];
            u32 x1 = g[(size_t)u1 * 64 + lane];
            u32 x2 = g[(size_t)u2 * 64 + lane];
            u32 x3 = g[(size_t)u3 * 64 + lane];
            u32 x4 = g[(size_t)u4 * 64 + lane];
            u32 x5 = g[(size_t)u5 * 64 + lane];
            u32 x6 = g[(size_t)u6 * 64 + lane];
            u32 x7 = g[(size_t)u7 * 64 + lane];
            a0x += bf_lo(x0);                a0y += bf_hi(x0);
            a1x = fmaf(w1, bf_lo(x1), a1x);  a1y = fmaf(w1, bf_hi(x1), a1y);
            a2x = fmaf(w2, bf_lo(x2), a2x);  a2y = fmaf(w2, bf_hi(x2), a2y);
            a3x = fmaf(w3, bf_lo(x3), a3x);  a3y = fmaf(w3, bf_hi(x3), a3y);
            a4x = fmaf(w4, bf_lo(x4), a4x);  a4y = fmaf(w4, bf_hi(x4), a4y);
            a5x = fmaf(w5, bf_lo(x5), a5x);  a5y = fmaf(w5, bf_hi(x5), a5y);
            a6x = fmaf(w6, bf_lo(x6), a6x);  a6y = fmaf(w6, bf_hi(x6), a6y);
            a7x = fmaf(w7, bf_lo(x7), a7x);  a7y = fmaf(w7, bf_hi(x7), a7y);
        }
    }
    float sx = ((a0x + a1x) + (a2x + a3x)) + ((a4x + a5x) + (a6x + a7x));
    float sy = ((a0y + a1y) + (a2y + a3y)) + ((a4y + a5y) + (a6y + a7y));
    const float dv = dinv[v];
    const float2 bb = *(const float2*)&b1[lane * 2];
    float o0 = fmaxf(fmaf(dv, sx, bb.x), 0.f);
    float o1 = fmaxf(fmaf(dv, sy, bb.y), 0.f);
    h1[(size_t)v * 64 + lane] = (u32)f2bf(o0) | ((u32)f2bf(o1) << 16);
}

__global__ __launch_bounds__(256) void agg2_kernel(const u16* __restrict__ g2,
                                                   const int* __restrict__ rowptr,
                                                   const int* __restrict__ col,
                                                   const float* __restrict__ dinv,
                                                   const float* __restrict__ b2f,
                                                   float* __restrict__ out, int n) {
    const int wid  = threadIdx.x >> 6;
    const int lane = threadIdx.x & 63;
    const int v = blockIdx.x * 4 + wid;
    if (v >= n) return;
    const int base = rowptr[v], endi = rowptr[v + 1];

    float a0 = __builtin_bit_cast(float, (u32)g2[(size_t)v * 64 + lane] << 16);
    float a1 = 0.f, a2 = 0.f, a3 = 0.f, a4 = 0.f, a5 = 0.f, a6 = 0.f, a7 = 0.f;

    for (int c = base; c < endi; c += 64) {
        const int m = min(64, endi - c);
        const int idx = col[c + min(lane, m - 1)];
        for (int i = 0; i < m; i += 8) {
            int u0 = __shfl(idx, i);
            int u1 = __shfl(idx, min(i + 1, m - 1));
            int u2 = __shfl(idx, min(i + 2, m - 1));
            int u3 = __shfl(idx, min(i + 3, m - 1));
            int u4 = __shfl(idx, min(i + 4, m - 1));
            int u5 = __shfl(idx, min(i + 5, m - 1));
            int u6 = __shfl(idx, min(i + 6, m - 1));
            int u7 = __shfl(idx, min(i + 7, m - 1));
            float w1 = (i + 1 < m) ? 1.f : 0.f;
            float w2 = (i + 2 < m) ? 1.f : 0.f;
            float w3 = (i + 3 < m) ? 1.f : 0.f;
            float w4 = (i + 4 < m) ? 1.f : 0.f;
            float w5 = (i + 5 < m) ? 1.f : 0.f;
            float w6 = (i + 6 < m) ? 1.f : 0.f;
            float w7 = (i + 7 < m) ? 1.f : 0.f;
            float x0 = __builtin_bit_cast(float, (u32)g2[(size_t)u0 * 64 + lane] << 16);
            float x1 = __builtin_bit_cast(float, (u32)g2[(size_t)u1 * 64 + lane] << 16);
            float x2 = __builtin_bit_cast(float, (u32)g2[(size_t)u2 * 64 + lane] << 16);
            float x3 = __builtin_bit_cast(float, (u32)g2[(size_t)u3 * 64 + lane] << 16);
            float x4 = __builtin_bit_cast(float, (u32)g2[(size_t)u4 * 64 + lane] << 16);
            float x5 = __builtin_bit_cast(float, (u32)g2[(size_t)u5 * 64 + lane] << 16);
            float x6 = __builtin_bit_cast(float, (u32)g2[(size_t)u6 * 64 + lane] << 16);
            float x7 = __builtin_bit_cast(float, (u32)g2[(size_t)u7 * 64 + lane] << 16);
            a0 += x0;
            a1 = fmaf(w1, x1, a1);
            a2 = fmaf(w2, x2, a2);
            a3 = fmaf(w3, x3, a3);
            a4 = fmaf(w4, x4, a4);
            a5 = fmaf(w5, x5, a5);
            a6 = fmaf(w6, x6, a6);
            a7 = fmaf(w7, x7, a7);
        }
    }
    float s = ((a0 + a1) + (a2 + a3)) + ((a4 + a5) + (a6 + a7));
    out[(size_t)v * OUTC + lane] = fmaf(dinv[v], s, b2f[lane]);
}

// ---------------- launch ----------------

extern "C" void kernel_launch(void* const* d_in, const int* in_sizes, int n_in,
                              void* d_out, int out_size, void* d_ws, size_t ws_size,
                              hipStream_t stream) {
    const float* x   = (const float*)d_in[0];
    const int*   ei  = (const int*)d_in[1];
    const float* W1  = (const float*)d_in[2];
    const float* b1  = (const float*)d_in[3];
    const float* W2  = (const float*)d_in[4];
    const float* b2  = (const float*)d_in[5];
    const float* Wfc = (const float*)d_in[6];
    const float* bfc = (const float*)d_in[7];
    float* out = (float*)d_out;

    const int n = in_sizes[0] / INC;
    const int E = in_sizes[1] / 2;
    const int* src = ei;
    const int* dst = ei + E;
    const int nb = (n + 255) >> BSH;

    char* w = (char*)d_ws;
    auto alloc = [&](size_t bytes) -> void* {
        void* p = (void*)w;
        w += (bytes + 255) & ~(size_t)255;
        return p;
    };
    int*   rowptr    = (int*)alloc((size_t)(n + 1) * 4);
    float* dinvp     = (float*)alloc((size_t)n * 4);
    int*   col       = (int*)alloc((size_t)E * 4);
    int2*  binned    = (int2*)alloc((size_t)E * 8);
    int*   parts     = (int*)alloc((size_t)NBMAX * HB * 4);
    int*   bucketOff = (int*)alloc((size_t)(nb + 1) * 4);
    int*   gfill     = (int*)alloc((size_t)nb * 4);
    u16*   g         = (u16*)alloc((size_t)n * HIDC * 2);   // bf16 g1, reused as g2
    u16*   h1        = (u16*)alloc((size_t)n * HIDC * 2);   // bf16 h1
    u16*   W1t       = (u16*)alloc((size_t)HIDC * HIDC * 2);
    u16*   W2ft      = (u16*)alloc((size_t)OUTC * HIDC * 2);
    float* b2f       = (float*)alloc((size_t)OUTC * 4);

    hipMemsetAsync(gfill, 0, (size_t)nb * 4, stream);

    fold_kernel<<<(HIDC * HIDC + HIDC * OUTC + OUTC + 255) / 256, 256, 0, stream>>>(
        W1, W2, Wfc, b2, bfc, W1t, W2ft, b2f);
    bhist_kernel<<<HB, 256, 0, stream>>>(dst, parts, E, nb);
    bscan_kernel<<<1, NBMAX, 0, stream>>>(parts, bucketOff, nb);
    multisplit_kernel<<<(E + TILE - 1) / TILE, 256, 0, stream>>>(src, dst, bucketOff, gfill, binned, E, nb);
    csr_build_kernel<<<nb, 256, 0, stream>>>(binned, bucketOff, col, rowptr, dinvp, n, E);

    // layer 1: g = bf16((x @ W1) * dinv) ; h1 = bf16(relu(dinv*(g[v]+sum g[u]) + b1))
    mfma_gemm_kernel<HIDC, true><<<(n + 63) / 64, 256, 0, stream>>>(x, W1t, dinvp, g, n);
    agg1_kernel<<<(n + 3) / 4, 256, 0, stream>>>((const u32*)g, rowptr, col, dinvp, b1, (u32*)h1, n);

    // layer 2 (+FC folded): g2 = bf16((h1 @ W2f) * dinv) ; out = dinv*(g2[v]+sum g2[u]) + b2f
    mfma_gemm_kernel<OUTC, false><<<(n + 63) / 64, 256, 0, stream>>>(h1, W2ft, dinvp, g, n);
    agg2_kernel<<<(n + 3) / 4, 256, 0, stream>>>(g, rowptr, col, dinvp, b2f, out, n);
}

// Round 7
// 197.003 us; speedup vs baseline: 3.9442x; 1.0453x over previous
//
#include <hip/hip_runtime.h>

#define INC  128
#define HIDC 128
#define OUTC 64

#define BSH   8        // bucket = dst >> 8 (256 nodes per bucket)
#define NBMAX 512      // supports n <= 131072
#define HB    128      // bhist blocks
#define TILE  4096     // edges per multisplit block
#define CAP   8192     // csr_build LDS col-stage capacity

typedef unsigned int  u32;
typedef unsigned short u16;
typedef short bf16x8 __attribute__((ext_vector_type(8)));
typedef float f32x4 __attribute__((ext_vector_type(4)));

static __device__ __forceinline__ u16 f2bf(float f) {
    u32 u = __builtin_bit_cast(u32, f);
    u += 0x7fffu + ((u >> 16) & 1u);
    return (u16)(u >> 16);
}
static __device__ __forceinline__ float bf_lo(u32 u) {
    return __builtin_bit_cast(float, u << 16);
}
static __device__ __forceinline__ float bf_hi(u32 u) {
    return __builtin_bit_cast(float, u & 0xffff0000u);
}

// ---------------- CSR build: bucket hist -> scan -> multisplit -> per-bucket CSR ----

__global__ __launch_bounds__(256) void bhist_kernel(const int* __restrict__ dst,
                                                    int* __restrict__ parts,  // [NBMAX][HB]
                                                    int E, int nb) {
    __shared__ int h[NBMAX];
    for (int i = threadIdx.x; i < NBMAX; i += 256) h[i] = 0;
    __syncthreads();
    const int total = HB * 256;
    for (int e = blockIdx.x * 256 + threadIdx.x; e < E; e += total)
        atomicAdd(&h[dst[e] >> BSH], 1);
    __syncthreads();
    for (int i = threadIdx.x; i < nb; i += 256) parts[i * HB + blockIdx.x] = h[i];
}

__global__ __launch_bounds__(512) void bscan_kernel(const int* __restrict__ parts,
                                                    int* __restrict__ bucketOff, int nb) {
    __shared__ int sums[NBMAX];
    const int tid = threadIdx.x;
    int s = 0;
    if (tid < nb) {
        const int* p = parts + tid * HB;
#pragma unroll 8
        for (int r = 0; r < HB; ++r) s += p[r];
    }
    sums[tid] = s;
    __syncthreads();
    for (int d = 1; d < NBMAX; d <<= 1) {
        int t = sums[tid];
        int a = (tid >= d) ? sums[tid - d] : 0;
        __syncthreads();
        sums[tid] = t + a;
        __syncthreads();
    }
    if (tid < nb) bucketOff[tid] = sums[tid] - s;
    if (tid == NBMAX - 1) bucketOff[nb] = sums[NBMAX - 1];
}

// binned element: src (low 24 bits) | (dst & 255) << 24
__global__ __launch_bounds__(256) void multisplit_kernel(const int* __restrict__ src,
                                                         const int* __restrict__ dst,
                                                         const int* __restrict__ bucketOff,
                                                         int* __restrict__ gfill,
                                                         u32* __restrict__ binned,
                                                         int E, int nb) {
    __shared__ int hist[NBMAX];
    __shared__ int sbase[NBMAX];
    __shared__ int cursor[NBMAX];
    __shared__ int gposs[NBMAX];
    __shared__ int wsum[4];
    __shared__ int2 buf[TILE];
    const int tid  = threadIdx.x;
    const int base = blockIdx.x * TILE;
    const int cnt  = min(TILE, E - base);

    for (int i = tid; i < NBMAX; i += 256) hist[i] = 0;
    __syncthreads();

    int ls[16], ld[16], dg[16];
#pragma unroll
    for (int k = 0; k < 16; ++k) {
        int idx = tid + k * 256;
        if (idx < cnt) {
            ls[k] = src[base + idx];
            ld[k] = dst[base + idx];
            dg[k] = ld[k] >> BSH;
            atomicAdd(&hist[dg[k]], 1);
        } else dg[k] = -1;
    }
    __syncthreads();
    {
        const int a = hist[2 * tid], b = hist[2 * tid + 1];
        const int s = a + b;
        const int lane = tid & 63;
        int incl = s;
#pragma unroll
        for (int d = 1; d < 64; d <<= 1) {
            int t = __shfl_up(incl, d);
            if (lane >= d) incl += t;
        }
        if (lane == 63) wsum[tid >> 6] = incl;
        __syncthreads();
        const int w = tid >> 6;
        int wbase = 0;
        if (w > 0) wbase += wsum[0];
        if (w > 1) wbase += wsum[1];
        if (w > 2) wbase += wsum[2];
        const int excl = wbase + incl - s;
        sbase[2 * tid] = excl;          cursor[2 * tid] = excl;
        sbase[2 * tid + 1] = excl + a;  cursor[2 * tid + 1] = excl + a;
    }
    __syncthreads();
#pragma unroll
    for (int k = 0; k < 16; ++k) {
        if (dg[k] >= 0) {
            int p = atomicAdd(&cursor[dg[k]], 1);
            buf[p] = make_int2(ls[k], ld[k]);
        }
    }
    __syncthreads();
    for (int d = tid; d < nb; d += 256) {
        int c = cursor[d] - sbase[d];
        gposs[d] = (c > 0) ? atomicAdd(&gfill[d], c) : 0;
    }
    __syncthreads();
    for (int idx = tid; idx < cnt; idx += 256) {
        int2 e = buf[idx];
        int d = e.y >> BSH;
        binned[bucketOff[d] + gposs[d] + (idx - sbase[d])] =
            (u32)e.x | ((u32)(e.y & 255) << 24);
    }
}

__global__ __launch_bounds__(256) void csr_build_kernel(const u32* __restrict__ binned,
                                                        const int* __restrict__ bucketOff,
                                                        int* __restrict__ col,
                                                        int* __restrict__ rowptr,
                                                        float* __restrict__ dinv,
                                                        int n, int E) {
    __shared__ int cnt[257];
    __shared__ int excl[256];
    __shared__ int wsum[4];
    __shared__ int colstage[CAP];
    const int tid   = threadIdx.x;
    const int b     = blockIdx.x;
    const int node0 = b << BSH;
    const int nNodes = min(256, n - node0);
    const int e0 = bucketOff[b], e1 = bucketOff[b + 1];
    const int ec = e1 - e0;

    for (int i = tid; i <= 256; i += 256) cnt[i] = 0;
    __syncthreads();
    for (int i = tid; i < ec; i += 256)
        atomicAdd(&cnt[binned[e0 + i] >> 24], 1);
    __syncthreads();
    const int myc = cnt[tid];
    {
        const int lane = tid & 63;
        int incl = myc;
#pragma unroll
        for (int d = 1; d < 64; d <<= 1) {
            int t = __shfl_up(incl, d);
            if (lane >= d) incl += t;
        }
        if (lane == 63) wsum[tid >> 6] = incl;
        __syncthreads();
        const int w = tid >> 6;
        int wbase = 0;
        if (w > 0) wbase += wsum[0];
        if (w > 1) wbase += wsum[1];
        if (w > 2) wbase += wsum[2];
        excl[tid] = wbase + incl - myc;
    }
    __syncthreads();
    if (tid < nNodes) {
        const int node = node0 + tid;
        rowptr[node] = e0 + excl[tid];
        dinv[node] = rsqrtf((float)(myc + 1));
    }
    if (b == 0 && tid == 0) rowptr[n] = E;
    __syncthreads();
    cnt[tid] = excl[tid];
    __syncthreads();
    if (ec <= CAP) {
        for (int i = tid; i < ec; i += 256) {
            u32 e = binned[e0 + i];
            int p = atomicAdd(&cnt[e >> 24], 1);
            colstage[p] = (int)(e & 0xffffffu);
        }
        __syncthreads();
        for (int i = tid; i < ec; i += 256) col[e0 + i] = colstage[i];
    } else {
        for (int i = tid; i < ec; i += 256) {
            u32 e = binned[e0 + i];
            int p = atomicAdd(&cnt[e >> 24], 1);
            col[e0 + p] = (int)(e & 0xffffffu);
        }
    }
}

// fold + convert: W1t_bf[n][k] = bf16(W1[k][n]); W2ft_bf[j][i] = bf16(sum_k W2[i][k]Wfc[k][j]);
// b2f = b2 @ Wfc + bfc (f32)
__global__ __launch_bounds__(256) void fold_kernel(const float* __restrict__ W1,
                                                   const float* __restrict__ W2,
                                                   const float* __restrict__ Wfc,
                                                   const float* __restrict__ b2,
                                                   const float* __restrict__ bfc,
                                                   u16* __restrict__ W1t,
                                                   u16* __restrict__ W2ft,
                                                   float* __restrict__ b2f) {
    int t = blockIdx.x * 256 + threadIdx.x;
    if (t < HIDC * HIDC) {                       // W1 transpose->bf16
        int nn = t >> 7, k = t & 127;
        W1t[nn * HIDC + k] = f2bf(W1[k * HIDC + nn]);
    } else if (t < HIDC * HIDC + HIDC * OUTC) {  // W2f fold, transposed bf16
        int u = t - HIDC * HIDC;
        int i = u >> 6, j = u & 63;
        float s = 0.f;
#pragma unroll 8
        for (int k = 0; k < OUTC; ++k) s = fmaf(W2[i * OUTC + k], Wfc[k * OUTC + j], s);
        W2ft[j * HIDC + i] = f2bf(s);
    } else if (t < HIDC * HIDC + HIDC * OUTC + OUTC) {
        int j = t - HIDC * HIDC - HIDC * OUTC;
        float s = bfc[j];
#pragma unroll 8
        for (int k = 0; k < OUTC; ++k) s = fmaf(b2[k], Wfc[k * OUTC + j], s);
        b2f[j] = s;
    }
}

// ---------------- MFMA bf16 GEMM: [M,128] @ [128,N] -> bf16 out scaled by dinv ----
// Row M (one past last) is written as ZEROS: sentinel row for the agg sentinel trick.

template <int N, bool AF32>
__global__ __launch_bounds__(256) void mfma_gemm_kernel(const void* __restrict__ Aptr,
                                                        const u16* __restrict__ Wt,
                                                        const float* __restrict__ dinv,
                                                        u16* __restrict__ out, int M) {
    constexpr int K = 128;
    constexpr int NC = N / 16;
    __shared__ u16 Ws[N * K];   // 16B slots: slot = n*16 + (c ^ (n&7))

    const int tid = threadIdx.x;
    for (int id = tid; id < N * K / 8; id += 256) {
        int nn = id >> 4;
        int c  = id & 15;
        uint4 v = *(const uint4*)(Wt + nn * K + c * 8);
        int slot = (nn << 4) + (c ^ (nn & 7));
        *(uint4*)((char*)Ws + slot * 16) = v;
    }

    const int wave = tid >> 6;
    const int lane = tid & 63;
    const int r0   = blockIdx.x * 64 + wave * 16;
    const int arow = r0 + (lane & 15);
    const int kgrp = lane >> 4;   // 0..3
    __syncthreads();

    f32x4 acc[NC];
#pragma unroll
    for (int nc = 0; nc < NC; ++nc) acc[nc] = f32x4{0.f, 0.f, 0.f, 0.f};

#pragma unroll
    for (int kc = 0; kc < 4; ++kc) {
        bf16x8 af = {0, 0, 0, 0, 0, 0, 0, 0};
        if (arow < M) {
            if constexpr (AF32) {
                const float* ap = (const float*)Aptr + (size_t)arow * K + kc * 32 + kgrp * 8;
                float4 v0 = *(const float4*)ap;
                float4 v1 = *(const float4*)(ap + 4);
                af[0] = (short)f2bf(v0.x); af[1] = (short)f2bf(v0.y);
                af[2] = (short)f2bf(v0.z); af[3] = (short)f2bf(v0.w);
                af[4] = (short)f2bf(v1.x); af[5] = (short)f2bf(v1.y);
                af[6] = (short)f2bf(v1.z); af[7] = (short)f2bf(v1.w);
            } else {
                af = *(const bf16x8*)((const u16*)Aptr + (size_t)arow * K + kc * 32 + kgrp * 8);
            }
        }
#pragma unroll
        for (int nc = 0; nc < NC; ++nc) {
            int nn = nc * 16 + (lane & 15);
            int slot = (nn << 4) + ((kc * 4 + kgrp) ^ (nn & 7));
            bf16x8 bfr = *(const bf16x8*)((const char*)Ws + slot * 16);
            acc[nc] = __builtin_amdgcn_mfma_f32_16x16x32_bf16(af, bfr, acc[nc], 0, 0, 0);
        }
    }
    // C/D: col = lane&15, row = (lane>>4)*4 + reg
#pragma unroll
    for (int reg = 0; reg < 4; ++reg) {
        int row = r0 + (lane >> 4) * 4 + reg;
        if (row <= M) {
            float sc = (row < M) ? dinv[row] : 0.f;   // row==M -> zero sentinel row
#pragma unroll
            for (int nc = 0; nc < NC; ++nc)
                out[(size_t)row * N + nc * 16 + (lane & 15)] = f2bf(acc[nc][reg] * sc);
        }
    }
}

// ---------------- aggregation: wave-split gathers, sentinel-padded chunks ----------
// agg1: 2 halves x 2 edges/step, 4 ch/lane (uint2).  row = 128 bf16 = 256B.

__global__ __launch_bounds__(256) void agg1_kernel(const u16* __restrict__ g,
                                                   const int* __restrict__ rowptr,
                                                   const int* __restrict__ col,
                                                   const float* __restrict__ dinv,
                                                   const float* __restrict__ b1,
                                                   u32* __restrict__ h1, int n) {
    const int wid  = threadIdx.x >> 6;
    const int lane = threadIdx.x & 63;
    const int v = blockIdx.x * 4 + wid;
    if (v >= n) return;
    const int h = lane >> 5;      // half: which edge of the pair
    const int r = lane & 31;      // channel group: ch 4r..4r+3
    const int base = rowptr[v], endi = rowptr[v + 1];

    float a0 = 0.f, a1 = 0.f, a2 = 0.f, a3 = 0.f;   // chain A
    float b0 = 0.f, b1v = 0.f, b2v = 0.f, b3 = 0.f; // chain B
    {   // self term, half 0 only
        uint2 sv = *(const uint2*)(g + ((size_t)v << 7) + (r << 2));
        if (h == 0) {
            a0 = bf_lo(sv.x); a1 = bf_hi(sv.x);
            a2 = bf_lo(sv.y); a3 = bf_hi(sv.y);
        }
    }

    for (int c = base; c < endi; c += 64) {
        const int m = min(64, endi - c);
        const int idx = (lane < m) ? col[c + lane] : n;   // clamp -> zero sentinel row
        for (int i = 0; i < m; i += 8) {
            int u0 = __shfl(idx, i + h);
            int u1 = __shfl(idx, i + 2 + h);
            int u2 = __shfl(idx, i + 4 + h);
            int u3 = __shfl(idx, i + 6 + h);
            uint2 x0 = *(const uint2*)(g + ((size_t)u0 << 7) + (r << 2));
            uint2 x1 = *(const uint2*)(g + ((size_t)u1 << 7) + (r << 2));
            uint2 x2 = *(const uint2*)(g + ((size_t)u2 << 7) + (r << 2));
            uint2 x3 = *(const uint2*)(g + ((size_t)u3 << 7) + (r << 2));
            a0 += bf_lo(x0.x); a1 += bf_hi(x0.x); a2 += bf_lo(x0.y); a3 += bf_hi(x0.y);
            b0 += bf_lo(x1.x); b1v += bf_hi(x1.x); b2v += bf_lo(x1.y); b3 += bf_hi(x1.y);
            a0 += bf_lo(x2.x); a1 += bf_hi(x2.x); a2 += bf_lo(x2.y); a3 += bf_hi(x2.y);
            b0 += bf_lo(x3.x); b1v += bf_hi(x3.x); b2v += bf_lo(x3.y); b3 += bf_hi(x3.y);
        }
    }
    float s0 = a0 + b0, s1 = a1 + b1v, s2 = a2 + b2v, s3 = a3 + b3;
    s0 += __shfl_xor(s0, 32);
    s1 += __shfl_xor(s1, 32);
    s2 += __shfl_xor(s2, 32);
    s3 += __shfl_xor(s3, 32);
    if (h == 0) {
        const float dv = dinv[v];
        const float4 bb = *(const float4*)&b1[r << 2];
        float o0 = fmaxf(fmaf(dv, s0, bb.x), 0.f);
        float o1 = fmaxf(fmaf(dv, s1, bb.y), 0.f);
        float o2 = fmaxf(fmaf(dv, s2, bb.z), 0.f);
        float o3 = fmaxf(fmaf(dv, s3, bb.w), 0.f);
        uint2 pk;
        pk.x = (u32)f2bf(o0) | ((u32)f2bf(o1) << 16);
        pk.y = (u32)f2bf(o2) | ((u32)f2bf(o3) << 16);
        *(uint2*)(h1 + ((size_t)v << 6) + (r << 1)) = pk;
    }
}

// agg2: 4 quarters x 4 edges/step, 4 ch/lane (uint2). row = 64 bf16 = 128B.
__global__ __launch_bounds__(256) void agg2_kernel(const u16* __restrict__ g2,
                                                   const int* __restrict__ rowptr,
                                                   const int* __restrict__ col,
                                                   const float* __restrict__ dinv,
                                                   const float* __restrict__ b2f,
                                                   float* __restrict__ out, int n) {
    const int wid  = threadIdx.x >> 6;
    const int lane = threadIdx.x & 63;
    const int v = blockIdx.x * 4 + wid;
    if (v >= n) return;
    const int q = lane >> 4;      // quarter: which edge of the 4
    const int r = lane & 15;      // channel group: ch 4r..4r+3
    const int base = rowptr[v], endi = rowptr[v + 1];

    float a0 = 0.f, a1 = 0.f, a2 = 0.f, a3 = 0.f;
    float b0 = 0.f, b1v = 0.f, b2v = 0.f, b3 = 0.f;
    {   // self term, quarter 0 only
        uint2 sv = *(const uint2*)(g2 + ((size_t)v << 6) + (r << 2));
        if (q == 0) {
            a0 = bf_lo(sv.x); a1 = bf_hi(sv.x);
            a2 = bf_lo(sv.y); a3 = bf_hi(sv.y);
        }
    }

    for (int c = base; c < endi; c += 64) {
        const int m = min(64, endi - c);
        const int idx = (lane < m) ? col[c + lane] : n;
        for (int i = 0; i < m; i += 8) {
            int u0 = __shfl(idx, i + q);        // edges i..i+3
            int u1 = __shfl(idx, i + 4 + q);    // edges i+4..i+7
            uint2 x0 = *(const uint2*)(g2 + ((size_t)u0 << 6) + (r << 2));
            uint2 x1 = *(const uint2*)(g2 + ((size_t)u1 << 6) + (r << 2));
            a0 += bf_lo(x0.x); a1 += bf_hi(x0.x); a2 += bf_lo(x0.y); a3 += bf_hi(x0.y);
            b0 += bf_lo(x1.x); b1v += bf_hi(x1.x); b2v += bf_lo(x1.y); b3 += bf_hi(x1.y);
        }
    }
    float s0 = a0 + b0, s1 = a1 + b1v, s2 = a2 + b2v, s3 = a3 + b3;
    s0 += __shfl_xor(s0, 16); s0 += __shfl_xor(s0, 32);
    s1 += __shfl_xor(s1, 16); s1 += __shfl_xor(s1, 32);
    s2 += __shfl_xor(s2, 16); s2 += __shfl_xor(s2, 32);
    s3 += __shfl_xor(s3, 16); s3 += __shfl_xor(s3, 32);
    if (q == 0) {
        const float dv = dinv[v];
        const float4 bb = *(const float4*)&b2f[r << 2];
        float4 o;
        o.x = fmaf(dv, s0, bb.x);
        o.y = fmaf(dv, s1, bb.y);
        o.z = fmaf(dv, s2, bb.z);
        o.w = fmaf(dv, s3, bb.w);
        *(float4*)(out + ((size_t)v << 6) + (r << 2)) = o;
    }
}

// ---------------- launch ----------------

extern "C" void kernel_launch(void* const* d_in, const int* in_sizes, int n_in,
                              void* d_out, int out_size, void* d_ws, size_t ws_size,
                              hipStream_t stream) {
    const float* x   = (const float*)d_in[0];
    const int*   ei  = (const int*)d_in[1];
    const float* W1  = (const float*)d_in[2];
    const float* b1  = (const float*)d_in[3];
    const float* W2  = (const float*)d_in[4];
    const float* b2  = (const float*)d_in[5];
    const float* Wfc = (const float*)d_in[6];
    const float* bfc = (const float*)d_in[7];
    float* out = (float*)d_out;

    const int n = in_sizes[0] / INC;
    const int E = in_sizes[1] / 2;
    const int* src = ei;
    const int* dst = ei + E;
    const int nb = (n + 255) >> BSH;

    char* w = (char*)d_ws;
    auto alloc = [&](size_t bytes) -> void* {
        void* p = (void*)w;
        w += (bytes + 255) & ~(size_t)255;
        return p;
    };
    int*   rowptr    = (int*)alloc((size_t)(n + 1) * 4);
    float* dinvp     = (float*)alloc((size_t)n * 4);
    int*   col       = (int*)alloc((size_t)(E + 64) * 4);
    u32*   binned    = (u32*)alloc((size_t)E * 4);
    int*   parts     = (int*)alloc((size_t)NBMAX * HB * 4);
    int*   bucketOff = (int*)alloc((size_t)(nb + 1) * 4);
    int*   gfill     = (int*)alloc((size_t)nb * 4);
    u16*   g         = (u16*)alloc((size_t)(n + 1) * HIDC * 2);  // bf16, +1 sentinel row
    u16*   h1        = (u16*)alloc((size_t)n * HIDC * 2);        // bf16 h1
    u16*   W1t       = (u16*)alloc((size_t)HIDC * HIDC * 2);
    u16*   W2ft      = (u16*)alloc((size_t)OUTC * HIDC * 2);
    float* b2f       = (float*)alloc((size_t)OUTC * 4);

    hipMemsetAsync(gfill, 0, (size_t)nb * 4, stream);

    fold_kernel<<<(HIDC * HIDC + HIDC * OUTC + OUTC + 255) / 256, 256, 0, stream>>>(
        W1, W2, Wfc, b2, bfc, W1t, W2ft, b2f);
    bhist_kernel<<<HB, 256, 0, stream>>>(dst, parts, E, nb);
    bscan_kernel<<<1, NBMAX, 0, stream>>>(parts, bucketOff, nb);
    multisplit_kernel<<<(E + TILE - 1) / TILE, 256, 0, stream>>>(src, dst, bucketOff, gfill, binned, E, nb);
    csr_build_kernel<<<nb, 256, 0, stream>>>(binned, bucketOff, col, rowptr, dinvp, n, E);

    // layer 1: g = bf16((x @ W1) * dinv), +zero sentinel row; h1 = bf16(relu(...))
    mfma_gemm_kernel<HIDC, true><<<(n + 64) / 64, 256, 0, stream>>>(x, W1t, dinvp, g, n);
    agg1_kernel<<<(n + 3) / 4, 256, 0, stream>>>(g, rowptr, col, dinvp, b1, (u32*)h1, n);

    // layer 2 (+FC folded): g2 = bf16((h1 @ W2f) * dinv), +zero sentinel row
    mfma_gemm_kernel<OUTC, false><<<(n + 64) / 64, 256, 0, stream>>>(h1, W2ft, dinvp, g, n);
    agg2_kernel<<<(n + 3) / 4, 256, 0, stream>>>(g, rowptr, col, dinvp, b2f, out, n);
}